// Round 1
// baseline (6249.417 us; speedup 1.0000x reference)
//
#include <hip/hip_runtime.h>
#include <math.h>

// Problem constants
#define BIMG 8
#define TPI  4096          // tokens per image
#define TT   32768         // total tokens
#define DIN  1176
#define DM   1024
#define NE   8
#define BN   64
#define NL   4
#define DOUT 4096

// ws layout (float elements)
//  H0:     0          .. 33554432
//  H1:     33554432   .. 67108864
//  btok:   67108864   (int[8*32768])
//  bw:     67371008   (float[8*32768])
//  Z=67633152: counts int[32] | sum_probs f[256] | mask_cnt f[256] | g f[8192]   (zeroed each launch)
//  rb:     67641888   (float[256])
//  total ≈ 270.6 MB
#define OFF_H1   33554432u
#define OFF_BTOK 67108864u
#define OFF_BW   67371008u
#define OFF_Z    67633152u
#define OFF_RB   67641888u

// ---------------- in_proj GEMM: H[32768,1024] = X[32768,1176] @ Win[1176,1024]
__global__ __launch_bounds__(256) void gemm_in_kernel(
    const float* __restrict__ X, const float* __restrict__ W, float* __restrict__ H)
{
    __shared__ __align__(16) float As[32][68];   // [k][m], row stride 68 (16B aligned)
    __shared__ __align__(16) float Bs[32][64];   // [k][n]
    const int tid = threadIdx.x;
    const int n0 = blockIdx.x * 64, m0 = blockIdx.y * 64;
    const int tr = tid >> 4, tc = tid & 15;
    float acc[4][4];
#pragma unroll
    for (int i = 0; i < 4; ++i)
#pragma unroll
        for (int j = 0; j < 4; ++j) acc[i][j] = 0.0f;

    const int lam = tid >> 2, lak = (tid & 3) * 8;    // A loader: row lam, k-sub lak..lak+7
    const int lbk = tid >> 3, lbn = (tid & 7) * 8;    // B loader: k-row lbk, n-sub lbn..lbn+7
    const float* xrow = X + (size_t)(m0 + lam) * DIN;

    for (int k0 = 0; k0 < DIN; k0 += 32) {
        float av[8];
#pragma unroll
        for (int i = 0; i < 8; ++i) {
            int k = k0 + lak + i;
            av[i] = (k < DIN) ? xrow[k] : 0.0f;
        }
#pragma unroll
        for (int i = 0; i < 8; ++i) As[lak + i][lam] = av[i];

        int kb = k0 + lbk;
        if (kb < DIN) {
            const float* wp = W + (size_t)kb * DM + n0 + lbn;
            *(float4*)&Bs[lbk][lbn]     = *(const float4*)wp;
            *(float4*)&Bs[lbk][lbn + 4] = *(const float4*)(wp + 4);
        } else {
#pragma unroll
            for (int i = 0; i < 8; ++i) Bs[lbk][lbn + i] = 0.0f;
        }
        __syncthreads();
#pragma unroll
        for (int kk = 0; kk < 32; ++kk) {
            float4 a4 = *(const float4*)&As[kk][tr * 4];
            float4 b4 = *(const float4*)&Bs[kk][tc * 4];
            const float aa[4] = {a4.x, a4.y, a4.z, a4.w};
            const float bb[4] = {b4.x, b4.y, b4.z, b4.w};
#pragma unroll
            for (int i = 0; i < 4; ++i)
#pragma unroll
                for (int j = 0; j < 4; ++j) acc[i][j] += aa[i] * bb[j];
        }
        __syncthreads();
    }
#pragma unroll
    for (int i = 0; i < 4; ++i)
#pragma unroll
        for (int j = 0; j < 4; ++j)
            H[(size_t)(m0 + tr * 4 + i) * DM + n0 + tc * 4 + j] = acc[i][j];
}

// ---------------- column mean: out[img][d] += (1/4096) * sum_{t-slice} H[img,t,d]
__global__ __launch_bounds__(256) void colmean_kernel(
    const float* __restrict__ Hc, float* __restrict__ outp)
{
    const int col = blockIdx.x * 256 + threadIdx.x;
    const int img = blockIdx.y;
    const int t0  = blockIdx.z * 256;
    const float* p = Hc + ((size_t)img * TPI + t0) * DM + col;
    float s = 0.0f;
#pragma unroll 8
    for (int t = 0; t < 256; ++t) s += p[(size_t)t * DM];
    atomicAdd(&outp[img * DM + col], s * (1.0f / 4096.0f));
}

// ---------------- skin head + router skin-bias rb[l][img][e]
__global__ __launch_bounds__(256) void skin_kernel(
    const float* __restrict__ g, const float* __restrict__ w_sc1, const float* __restrict__ b_sc1,
    const float* __restrict__ w_sc2, const float* __restrict__ b_sc2,
    const float* __restrict__ w_rskin, float* __restrict__ skin_logits_out, float* __restrict__ rb)
{
    __shared__ float hs[512];
    __shared__ float l3[24];
    __shared__ float sp[24];
    const int tid = threadIdx.x;
#pragma unroll
    for (int h = 0; h < 2; ++h) {
        int idx = tid + h * 256;
        int img = idx >> 6, c = idx & 63;
        float s = b_sc1[c];
        for (int d = 0; d < DM; ++d) s += g[img * DM + d] * w_sc1[d * 64 + c];
        hs[idx] = fmaxf(s, 0.0f);
    }
    __syncthreads();
    if (tid < 24) {
        int img = tid / 3, j = tid % 3;
        float s = b_sc2[j];
        for (int c = 0; c < 64; ++c) s += hs[img * 64 + c] * w_sc2[c * 3 + j];
        l3[tid] = s;
        skin_logits_out[tid] = s;
    }
    __syncthreads();
    if (tid < 8) {
        float v0 = l3[tid * 3], v1 = l3[tid * 3 + 1], v2 = l3[tid * 3 + 2];
        float m = fmaxf(v0, fmaxf(v1, v2));
        float e0 = expf(v0 - m), e1 = expf(v1 - m), e2 = expf(v2 - m);
        float inv = 1.0f / (e0 + e1 + e2);
        sp[tid * 3] = e0 * inv; sp[tid * 3 + 1] = e1 * inv; sp[tid * 3 + 2] = e2 * inv;
    }
    __syncthreads();
    {   // tid = l*64 + img*8 + e exactly
        int l = tid >> 6, img = (tid >> 3) & 7, e = tid & 7;
        float s = 0.0f;
#pragma unroll
        for (int c = 0; c < 3; ++c) s += sp[img * 3 + c] * w_rskin[(l * 3 + c) * 8 + e];
        rb[tid] = s;
    }
}

// ---------------- router: logits -> softmax -> top2 -> buckets + aux sums; also Hcopy = Hin
__global__ __launch_bounds__(256) void router_kernel(
    const float* __restrict__ Hin, float* __restrict__ Hcopy,
    const float* __restrict__ w_rimg, const float* __restrict__ rb,
    int* __restrict__ counts, int* __restrict__ btok, float* __restrict__ bw,
    float* __restrict__ sum_probs, float* __restrict__ mask_cnt, int l)
{
    __shared__ float wl[DM * NE];        // 32 KB
    __shared__ float hs[64 * 65];        // 16.6 KB
    __shared__ float lgS[64 * 8];
    const int tid  = threadIdx.x;
    const int tok0 = blockIdx.x * 64;
    const int img  = tok0 >> 12;

    const float* wr = w_rimg + (size_t)l * DM * NE;
#pragma unroll
    for (int i = 0; i < 32; ++i) wl[tid + 256 * i] = wr[tid + 256 * i];

    const int tok = tid & 63, ep = tid >> 6;
    const int e0 = ep * 2, e1v = e0 + 1;
    float a0 = 0.0f, a1 = 0.0f;
    for (int ds = 0; ds < 16; ++ds) {
        __syncthreads();
#pragma unroll
        for (int i = 0; i < 16; ++i) {
            int flat = tid + 256 * i;          // 0..4095
            int r = flat >> 6, c = flat & 63;
            size_t gidx = (size_t)(tok0 + r) * DM + ds * 64 + c;
            float v = Hin[gidx];
            hs[r * 65 + c] = v;
            Hcopy[gidx] = v;
        }
        __syncthreads();
#pragma unroll
        for (int d = 0; d < 64; ++d) {
            float hv = hs[tok * 65 + d];
            int gd = ds * 64 + d;
            a0 += hv * wl[gd * 8 + e0];
            a1 += hv * wl[gd * 8 + e1v];
        }
    }
    lgS[tok * 8 + e0]  = a0;
    lgS[tok * 8 + e1v] = a1;
    __syncthreads();

    if (tid < 64) {   // wave 0, all 64 lanes active
        const int token = tok0 + tid;
        float p[8];
        float mx = -1e30f;
#pragma unroll
        for (int e = 0; e < 8; ++e) {
            float v = lgS[tid * 8 + e] + rb[l * 64 + img * 8 + e];
            p[e] = v; mx = fmaxf(mx, v);
        }
        float s = 0.0f;
#pragma unroll
        for (int e = 0; e < 8; ++e) { p[e] = expf(p[e] - mx); s += p[e]; }
        float inv = 1.0f / s;
#pragma unroll
        for (int e = 0; e < 8; ++e) p[e] *= inv;

        int i1 = 0; float b1v = p[0];
#pragma unroll
        for (int e = 1; e < 8; ++e) if (p[e] > b1v) { b1v = p[e]; i1 = e; }
        int i2 = -1; float b2v = -1.0f;
#pragma unroll
        for (int e = 0; e < 8; ++e) if (e != i1 && p[e] > b2v) { b2v = p[e]; i2 = e; }
        float den = b1v + b2v + 1e-6f;
        float w1 = b1v / den, w2 = b2v / den;

        for (int slot = 0; slot < 2; ++slot) {
            int   esel = slot ? i2 : i1;
            float wsel = slot ? w2 : w1;
            for (int e = 0; e < 8; ++e) {
                unsigned long long m = __ballot(esel == e);
                int pc = __popcll(m);
                if (pc) {
                    int leader = __ffsll(m) - 1;
                    int basep = 0;
                    if (tid == leader) basep = atomicAdd(&counts[l * 8 + e], pc);
                    basep = __shfl(basep, leader);
                    if (esel == e) {
                        int pos = basep + __popcll(m & ((1ull << tid) - 1ull));
                        btok[(e << 15) + pos] = token;
                        bw[(e << 15) + pos]   = wsel;
                    }
                    if (tid == leader)
                        atomicAdd(&mask_cnt[l * 64 + img * 8 + e], (float)pc);
                }
            }
        }
#pragma unroll
        for (int e = 0; e < 8; ++e) {
            float r = p[e];
            for (int off = 32; off > 0; off >>= 1) r += __shfl_down(r, off);
            if (tid == 0) atomicAdd(&sum_probs[l * 64 + img * 8 + e], r);
        }
    }
}

// ---------------- grouped expert MLP: gather 64 toks of expert e, h1=relu(h@W1+b1),
// scatter w*(h1@W2+b2) into Hout via atomicAdd
__global__ __launch_bounds__(256) void expert_kernel(
    const float* __restrict__ Hin, float* __restrict__ Hout,
    const int* __restrict__ counts, const int* __restrict__ btok, const float* __restrict__ bw,
    const float* __restrict__ ew1, const float* __restrict__ eb1,
    const float* __restrict__ ew2, const float* __restrict__ eb2, int l)
{
    const int e = blockIdx.y;
    const int cnt = counts[l * 8 + e];
    const int base = blockIdx.x * 64;
    if (base >= cnt) return;
    const int n_act = min(64, cnt - base);

    __shared__ __align__(16) float hA[32][68];    // [k][tok]
    __shared__ __align__(16) float ws1[32][64];   // [k][bn]
    __shared__ __align__(16) float h1t[64][68];   // [bn][tok]
    __shared__ __align__(16) float ws2[64][64];   // [bn][n]
    __shared__ int   tkS[64];
    __shared__ float wtS[64];

    const int tid = threadIdx.x;
    if (tid < 64) {
        bool valid = tid < n_act;
        tkS[tid] = valid ? btok[(e << 15) + base + tid] : -1;
        wtS[tid] = valid ? bw[(e << 15) + base + tid] : 0.0f;
    }
    __syncthreads();

    const int we = l * 8 + e;
    const float* W1 = ew1 + (size_t)we * DM * BN;
    const float* B1 = eb1 + we * BN;
    const float* W2 = ew2 + (size_t)we * BN * DM;
    const float* B2 = eb2 + we * DM;

    const int tr = tid >> 4, tc = tid & 15;
    float acc[4][4];
#pragma unroll
    for (int i = 0; i < 4; ++i)
#pragma unroll
        for (int j = 0; j < 4; ++j) acc[i][j] = 0.0f;

    const int ltok = tid >> 2, lkq = (tid & 3) * 8;
    const int lb = tid >> 3, lbn = (tid & 7) * 8;

    // ---- phase 1: h1[64 tok][64 bn]
    for (int k0 = 0; k0 < DM; k0 += 32) {
        float av[8];
        int t = tkS[ltok];
        if (t >= 0) {
            const float* hp = Hin + (size_t)t * DM + k0 + lkq;
            float4 u0 = *(const float4*)hp;
            float4 u1 = *(const float4*)(hp + 4);
            av[0] = u0.x; av[1] = u0.y; av[2] = u0.z; av[3] = u0.w;
            av[4] = u1.x; av[5] = u1.y; av[6] = u1.z; av[7] = u1.w;
        } else {
#pragma unroll
            for (int i = 0; i < 8; ++i) av[i] = 0.0f;
        }
#pragma unroll
        for (int i = 0; i < 8; ++i) hA[lkq + i][ltok] = av[i];

        const float* wp = W1 + (size_t)(k0 + lb) * BN + lbn;
        *(float4*)&ws1[lb][lbn]     = *(const float4*)wp;
        *(float4*)&ws1[lb][lbn + 4] = *(const float4*)(wp + 4);
        __syncthreads();
#pragma unroll
        for (int kk = 0; kk < 32; ++kk) {
            float4 a4 = *(const float4*)&hA[kk][tr * 4];
            float4 b4 = *(const float4*)&ws1[kk][tc * 4];
            const float aa[4] = {a4.x, a4.y, a4.z, a4.w};
            const float bb[4] = {b4.x, b4.y, b4.z, b4.w};
#pragma unroll
            for (int i = 0; i < 4; ++i)
#pragma unroll
                for (int j = 0; j < 4; ++j) acc[i][j] += aa[i] * bb[j];
        }
        __syncthreads();
    }
    // bias + relu, store transposed h1t[bn][tok]
#pragma unroll
    for (int i = 0; i < 4; ++i)
#pragma unroll
        for (int j = 0; j < 4; ++j) {
            float v = acc[i][j] + B1[tc * 4 + j];
            h1t[tc * 4 + j][tr * 4 + i] = fmaxf(v, 0.0f);
        }

    // ---- phase 2: out[64 tok][1024] in n-slices of 64
    for (int n0 = 0; n0 < DM; n0 += 64) {
        __syncthreads();   // protects h1t (first iter) and ws2 reuse
#pragma unroll
        for (int i = 0; i < 4; ++i) {
            int f4 = tid + 256 * i;            // 0..1023 float4s
            int b = f4 >> 4, n4 = (f4 & 15) * 4;
            *(float4*)&ws2[b][n4] = *(const float4*)(W2 + (size_t)b * DM + n0 + n4);
        }
        __syncthreads();
        float a2[4][4];
#pragma unroll
        for (int i = 0; i < 4; ++i)
#pragma unroll
            for (int j = 0; j < 4; ++j) a2[i][j] = 0.0f;
#pragma unroll 4
        for (int b = 0; b < 64; ++b) {
            float4 a4 = *(const float4*)&h1t[b][tr * 4];
            float4 b4 = *(const float4*)&ws2[b][tc * 4];
            const float aa[4] = {a4.x, a4.y, a4.z, a4.w};
            const float bb[4] = {b4.x, b4.y, b4.z, b4.w};
#pragma unroll
            for (int i = 0; i < 4; ++i)
#pragma unroll
                for (int j = 0; j < 4; ++j) a2[i][j] += aa[i] * bb[j];
        }
#pragma unroll
        for (int i = 0; i < 4; ++i) {
            int tkk = tr * 4 + i;
            if (tkk < n_act) {
                int t = tkS[tkk];
                float w = wtS[tkk];
#pragma unroll
                for (int j = 0; j < 4; ++j) {
                    int n = n0 + tc * 4 + j;
                    atomicAdd(&Hout[(size_t)t * DM + n], w * (a2[i][j] + B2[n]));
                }
            }
        }
    }
}

// ---------------- vision_proj: out1[img][n] = pooled[img]@w_out[:,n] + b_out[n]  (d-split, atomic)
__global__ __launch_bounds__(256) void vproj_kernel(
    const float* __restrict__ pooled, const float* __restrict__ w_out,
    const float* __restrict__ b_out, float* __restrict__ outp)
{
    __shared__ float ps[8 * 128];
    const int tid = threadIdx.x;
    const int n = blockIdx.x * 256 + tid;
    const int d0 = blockIdx.y * 128;
#pragma unroll
    for (int i = 0; i < 4; ++i) {
        int idx = tid + i * 256;
        int img = idx >> 7, d = idx & 127;
        ps[idx] = pooled[img * DM + d0 + d];
    }
    __syncthreads();
    float acc[8];
    float binit = (blockIdx.y == 0) ? b_out[n] : 0.0f;
#pragma unroll
    for (int img = 0; img < 8; ++img) acc[img] = binit;
    for (int d = 0; d < 128; ++d) {
        float wv = w_out[(size_t)(d0 + d) * DOUT + n];
#pragma unroll
        for (int img = 0; img < 8; ++img) acc[img] += ps[img * 128 + d] * wv;
    }
#pragma unroll
    for (int img = 0; img < 8; ++img) atomicAdd(&outp[img * DOUT + n], acc[img]);
}

// ---------------- aux = sum_{l,img} (8/T^2) * sum_e sp[l,img,e]*cnt[l,img,e]
__global__ __launch_bounds__(64) void aux_kernel(
    const float* __restrict__ sum_probs, const float* __restrict__ mask_cnt,
    float* __restrict__ outp)
{
    const int tid = threadIdx.x;
    float v = 0.0f;
    if (tid < 32) {   // tid = l*8 + img
        float s = 0.0f;
#pragma unroll
        for (int e = 0; e < 8; ++e) s += sum_probs[tid * 8 + e] * mask_cnt[tid * 8 + e];
        v = s * (8.0f / (4096.0f * 4096.0f));
    }
    for (int off = 32; off > 0; off >>= 1) v += __shfl_down(v, off);
    if (tid == 0) outp[0] = v;
}

extern "C" void kernel_launch(void* const* d_in, const int* in_sizes, int n_in,
                              void* d_out, int out_size, void* d_ws, size_t ws_size,
                              hipStream_t stream) {
    const float* X       = (const float*)d_in[0];
    // d_in[1] image_grid_thw: unused (equal chunks)
    const float* w_in    = (const float*)d_in[2];
    const float* w_sc1   = (const float*)d_in[3];
    const float* b_sc1   = (const float*)d_in[4];
    const float* w_sc2   = (const float*)d_in[5];
    const float* b_sc2   = (const float*)d_in[6];
    const float* w_rimg  = (const float*)d_in[7];
    const float* w_rskin = (const float*)d_in[8];
    const float* ew1     = (const float*)d_in[9];
    const float* eb1     = (const float*)d_in[10];
    const float* ew2     = (const float*)d_in[11];
    const float* eb2     = (const float*)d_in[12];
    const float* w_out   = (const float*)d_in[13];
    const float* b_out   = (const float*)d_in[14];

    float* out = (float*)d_out;
    float* ws  = (float*)d_ws;

    float* H0        = ws;
    float* H1        = ws + OFF_H1;
    int*   btok      = (int*)(ws + OFF_BTOK);
    float* bwp       = ws + OFF_BW;
    int*   counts    = (int*)(ws + OFF_Z);
    float* sum_probs = ws + OFF_Z + 32;
    float* mask_cnt  = ws + OFF_Z + 288;
    float* g         = ws + OFF_Z + 544;
    float* rb        = ws + OFF_RB;

    // zero outputs (pooled/vproj accumulated atomically) + counts/aux/g
    hipMemsetAsync(d_out, 0, (size_t)out_size * sizeof(float), stream);
    hipMemsetAsync(ws + OFF_Z, 0, 8736 * sizeof(float), stream);

    dim3 b256(256);
    gemm_in_kernel<<<dim3(16, 512), b256, 0, stream>>>(X, w_in, H0);
    colmean_kernel<<<dim3(4, 8, 16), b256, 0, stream>>>(H0, g);
    skin_kernel<<<1, b256, 0, stream>>>(g, w_sc1, b_sc1, w_sc2, b_sc2, w_rskin,
                                        out + 40961, rb);
    float* Hc = H0;
    float* Hn = H1;
    for (int l = 0; l < NL; ++l) {
        router_kernel<<<512, b256, 0, stream>>>(Hc, Hn, w_rimg, rb, counts, btok, bwp,
                                                sum_probs, mask_cnt, l);
        expert_kernel<<<dim3(512, 8), b256, 0, stream>>>(Hc, Hn, counts, btok, bwp,
                                                         ew1, eb1, ew2, eb2, l);
        float* tmp = Hc; Hc = Hn; Hn = tmp;
    }
    colmean_kernel<<<dim3(4, 8, 16), b256, 0, stream>>>(Hc, out);          // pooled
    vproj_kernel<<<dim3(16, 8), b256, 0, stream>>>(out, w_out, b_out, out + 8192);
    aux_kernel<<<1, 64, 0, stream>>>(sum_probs, mask_cnt, out + 40960);
}

// Round 2
// 1968.598 us; speedup vs baseline: 3.1746x; 3.1746x over previous
//
#include <hip/hip_runtime.h>
#include <math.h>

#define TPI  4096
#define TT   32768
#define DIN  1176
#define KP   1184          // DIN padded to x32
#define DM   1024
#define NE   8
#define BN   64
#define NL   4
#define DOUT 4096

typedef __attribute__((ext_vector_type(4))) float floatx4;
typedef __attribute__((ext_vector_type(8))) short bf16x8;
typedef unsigned int uint;

__device__ inline short f2bf(float x) {
    unsigned u = __float_as_uint(x);
    u += 0x7fffu + ((u >> 16) & 1u);
    return (short)(u >> 16);
}
__device__ inline float bf2f(short h) {
    return __uint_as_float(((unsigned)(unsigned short)h) << 16);
}

#define GLP(p) ((const __attribute__((address_space(1))) void*)(p))
#define LDSP(p) ((__attribute__((address_space(3))) void*)(p))
#define ASYNC16(g, s) __builtin_amdgcn_global_load_lds(GLP(g), LDSP(s), 16, 0, 0)

// ws layout (bytes)
#define OFF_HB    0ul
#define OFF_BUF   67108864ul      // 134217728 B ; Xb (77.6 MB) aliases this
#define OFF_WBT   201326592ul     // 1024*1184*2
#define OFF_EW1T  203751424ul     // 32*64*1024*2
#define OFF_EW2T  207945728ul     // 32*1024*64*2
#define OFF_BTOK  212140032ul     // int[65536]
#define OFF_BW    212402176ul     // float[65536]
#define OFF_SLOT  212664320ul     // int[65536]
#define OFF_T2E   212926464ul     // uint[32768]
#define OFF_T2W   213057536ul     // float[65536]
#define OFF_Z     213319680ul     // counts i32[32] | cursors i32[32] | sum_probs f[256] | mask_cnt f[256] | g f[8192]
#define Z_BYTES   35072ul

// ---------- convert X (f32, 32768x1176) -> Xb (bf16, 32768x1184, zero-padded)
__global__ __launch_bounds__(256) void convx_kernel(
    const float* __restrict__ X, short* __restrict__ Xb)
{
    const long row = blockIdx.x;
    const float* src = X + row * (long)DIN;
    short* dst = Xb + row * (long)KP;
    for (int c = threadIdx.x; c < KP; c += 256)
        dst[c] = (c < DIN) ? f2bf(src[c]) : (short)0;
}

// ---------- generic transpose: dst[n][k] (row len DK) = src[k][n]; src RS x CS, batched over z
__global__ __launch_bounds__(256) void transp_kernel(
    const float* __restrict__ src, short* __restrict__ dst, int RS, int CS, int DK)
{
    __shared__ float tb[64][65];
    const int kt = blockIdx.x * 64, nt = blockIdx.y * 64;
    const long sb = (long)blockIdx.z * RS * CS;
    const long db = (long)blockIdx.z * CS * DK;
    const int rr = threadIdx.x >> 6, cc = threadIdx.x & 63;
#pragma unroll
    for (int i = 0; i < 16; ++i) {
        int r = i * 4 + rr;
        int k = kt + r, n = nt + cc;
        tb[r][cc] = (k < RS && n < CS) ? src[sb + (long)k * CS + n] : 0.0f;
    }
    __syncthreads();
#pragma unroll
    for (int i = 0; i < 16; ++i) {
        int r = i * 4 + rr;
        int n = nt + r, k = kt + cc;
        if (n < CS && k < DK) dst[db + (long)n * DK + k] = f2bf(tb[cc][r]);
    }
}

// ---------- in_proj MFMA GEMM: Hb[32768,1024] = Xb[32768,KP] @ WbT[1024,KP]^T
__global__ __launch_bounds__(256) void gemm_in_mfma(
    const short* __restrict__ Xb, const short* __restrict__ Wbt, short* __restrict__ Hb)
{
    __shared__ __align__(16) short As[128 * 32];
    __shared__ __align__(16) short Bs[128 * 32];
    const int tid = threadIdx.x;
    const int n0 = blockIdx.x * 128, m0 = blockIdx.y * 128;
    const int w = tid >> 6, lane = tid & 63;
    const int quad = lane >> 4, l15 = lane & 15;
    const int wm = (w >> 1) * 64, wn = (w & 1) * 64;

    floatx4 acc[4][4];
#pragma unroll
    for (int i = 0; i < 4; ++i)
#pragma unroll
        for (int j = 0; j < 4; ++j) acc[i][j] = 0.0f;

    const int r0 = tid >> 2, kof = (tid & 3) * 8;
    const int r1 = (tid + 256) >> 2;
    const short* a0p = Xb + (long)(m0 + r0) * KP + kof;
    const short* a1p = Xb + (long)(m0 + r1) * KP + kof;
    const short* b0p = Wbt + (long)(n0 + r0) * KP + kof;
    const short* b1p = Wbt + (long)(n0 + r1) * KP + kof;
    short* as0 = As + tid * 8;
    short* as1 = As + (tid + 256) * 8;
    short* bs0 = Bs + tid * 8;
    short* bs1 = Bs + (tid + 256) * 8;

    for (int k0 = 0; k0 < KP; k0 += 32) {
        __syncthreads();
        ASYNC16(a0p + k0, as0);
        ASYNC16(a1p + k0, as1);
        ASYNC16(b0p + k0, bs0);
        ASYNC16(b1p + k0, bs1);
        __syncthreads();
        bf16x8 af[4], bfr[4];
#pragma unroll
        for (int i = 0; i < 4; ++i)
            af[i] = *(const bf16x8*)&As[(wm + i * 16 + l15) * 32 + quad * 8];
#pragma unroll
        for (int j = 0; j < 4; ++j)
            bfr[j] = *(const bf16x8*)&Bs[(wn + j * 16 + l15) * 32 + quad * 8];
#pragma unroll
        for (int i = 0; i < 4; ++i)
#pragma unroll
            for (int j = 0; j < 4; ++j)
                acc[i][j] = __builtin_amdgcn_mfma_f32_16x16x32_bf16(af[i], bfr[j], acc[i][j], 0, 0, 0);
    }
#pragma unroll
    for (int i = 0; i < 4; ++i)
#pragma unroll
        for (int j = 0; j < 4; ++j)
#pragma unroll
            for (int r = 0; r < 4; ++r)
                Hb[(long)(m0 + wm + i * 16 + quad * 4 + r) * DM + n0 + wn + j * 16 + l15] =
                    f2bf(acc[i][j][r]);
}

// ---------- column mean of Hb (bf16) into f32 dest (atomic over t-slices)
__global__ __launch_bounds__(256) void colmean_kernel(
    const short* __restrict__ Hb, float* __restrict__ outp)
{
    const int col = blockIdx.x * 256 + threadIdx.x;
    const int img = blockIdx.y;
    const int t0 = blockIdx.z * 256;
    const short* p = Hb + ((long)img * TPI + t0) * DM + col;
    float s = 0.0f;
#pragma unroll 8
    for (int t = 0; t < 256; ++t) s += bf2f(p[(long)t * DM]);
    atomicAdd(&outp[img * DM + col], s * (1.0f / 4096.0f));
}

// ---------- skin head + router skin-bias rb[l][img][e]
__global__ __launch_bounds__(256) void skin_kernel(
    const float* __restrict__ g, const float* __restrict__ w_sc1, const float* __restrict__ b_sc1,
    const float* __restrict__ w_sc2, const float* __restrict__ b_sc2,
    const float* __restrict__ w_rskin, float* __restrict__ skin_logits_out, float* __restrict__ rb)
{
    __shared__ float hs[512];
    __shared__ float l3[24];
    __shared__ float sp[24];
    const int tid = threadIdx.x;
#pragma unroll
    for (int h = 0; h < 2; ++h) {
        int idx = tid + h * 256;
        int img = idx >> 6, c = idx & 63;
        float s = b_sc1[c];
        for (int d = 0; d < DM; ++d) s += g[img * DM + d] * w_sc1[d * 64 + c];
        hs[idx] = fmaxf(s, 0.0f);
    }
    __syncthreads();
    if (tid < 24) {
        int img = tid / 3, j = tid % 3;
        float s = b_sc2[j];
        for (int c = 0; c < 64; ++c) s += hs[img * 64 + c] * w_sc2[c * 3 + j];
        l3[tid] = s;
        skin_logits_out[tid] = s;
    }
    __syncthreads();
    if (tid < 8) {
        float v0 = l3[tid * 3], v1 = l3[tid * 3 + 1], v2 = l3[tid * 3 + 2];
        float m = fmaxf(v0, fmaxf(v1, v2));
        float e0 = expf(v0 - m), e1 = expf(v1 - m), e2 = expf(v2 - m);
        float inv = 1.0f / (e0 + e1 + e2);
        sp[tid * 3] = e0 * inv; sp[tid * 3 + 1] = e1 * inv; sp[tid * 3 + 2] = e2 * inv;
    }
    __syncthreads();
    {
        int l = tid >> 6, img = (tid >> 3) & 7, e = tid & 7;
        float s = 0.0f;
#pragma unroll
        for (int c = 0; c < 3; ++c) s += sp[img * 3 + c] * w_rskin[(l * 3 + c) * 8 + e];
        rb[tid] = s;
    }
}

// ---------- router: logits -> softmax -> top2 record + aux accumulators
__global__ __launch_bounds__(256) void router_kernel(
    const short* __restrict__ Hb, const float* __restrict__ w_rimg, const float* __restrict__ rb,
    uint* __restrict__ top2e, float* __restrict__ top2w,
    int* __restrict__ counts, float* __restrict__ sum_probs, float* __restrict__ mask_cnt, int l)
{
    __shared__ float wl[DM * NE];          // 32 KB
    __shared__ __align__(16) short hs[64 * 64];
    __shared__ float lgS[64 * 8];
    const int tid = threadIdx.x;
    const int tok0 = blockIdx.x * 64;
    const int img = tok0 >> 12;

    const float* wr = w_rimg + (long)l * DM * NE;
#pragma unroll
    for (int i = 0; i < 32; ++i) wl[tid + 256 * i] = wr[tid + 256 * i];

    const int tok = tid & 63, ep = tid >> 6, e0 = ep * 2;
    const int c0 = tid, c1 = tid + 256;
    const short* g0 = Hb + (long)(tok0 + (c0 >> 3)) * DM + (c0 & 7) * 8;
    const short* g1 = Hb + (long)(tok0 + (c1 >> 3)) * DM + (c1 & 7) * 8;
    short* s0 = hs + c0 * 8;
    short* s1 = hs + c1 * 8;

    float a0 = 0.0f, a1 = 0.0f;
    for (int ds = 0; ds < 16; ++ds) {
        __syncthreads();
        ASYNC16(g0 + ds * 64, s0);
        ASYNC16(g1 + ds * 64, s1);
        __syncthreads();
#pragma unroll
        for (int d8 = 0; d8 < 8; ++d8) {
            bf16x8 h8 = *(const bf16x8*)&hs[tok * 64 + d8 * 8];
#pragma unroll
            for (int jj = 0; jj < 8; ++jj) {
                float hv = bf2f(h8[jj]);
                int gd = ds * 64 + d8 * 8 + jj;
                a0 += hv * wl[gd * 8 + e0];
                a1 += hv * wl[gd * 8 + e0 + 1];
            }
        }
    }
    lgS[tok * 8 + e0] = a0;
    lgS[tok * 8 + e0 + 1] = a1;
    __syncthreads();

    if (tid < 64) {
        const int token = tok0 + tid;
        float p[8];
        float mx = -1e30f;
#pragma unroll
        for (int e = 0; e < 8; ++e) {
            float v = lgS[tid * 8 + e] + rb[l * 64 + img * 8 + e];
            p[e] = v; mx = fmaxf(mx, v);
        }
        float s = 0.0f;
#pragma unroll
        for (int e = 0; e < 8; ++e) { p[e] = expf(p[e] - mx); s += p[e]; }
        float inv = 1.0f / s;
#pragma unroll
        for (int e = 0; e < 8; ++e) p[e] *= inv;

        int i1 = 0; float b1v = p[0];
#pragma unroll
        for (int e = 1; e < 8; ++e) if (p[e] > b1v) { b1v = p[e]; i1 = e; }
        int i2 = -1; float b2v = -1.0f;
#pragma unroll
        for (int e = 0; e < 8; ++e) if (e != i1 && p[e] > b2v) { b2v = p[e]; i2 = e; }
        float den = b1v + b2v + 1e-6f;
        top2e[token] = (uint)i1 | ((uint)i2 << 8);
        top2w[2 * token] = b1v / den;
        top2w[2 * token + 1] = b2v / den;

        // counts + mask_cnt via ballot aggregation
        for (int slot = 0; slot < 2; ++slot) {
            int esel = slot ? i2 : i1;
#pragma unroll
            for (int e = 0; e < 8; ++e) {
                unsigned long long m = __ballot(esel == e);
                int pc = __popcll(m);
                if (pc && tid == (__ffsll(m) - 1)) {
                    atomicAdd(&counts[l * 8 + e], pc);
                    atomicAdd(&mask_cnt[l * 64 + img * 8 + e], (float)pc);
                }
            }
        }
#pragma unroll
        for (int e = 0; e < 8; ++e) {
            float r = p[e];
            for (int off = 32; off > 0; off >>= 1) r += __shfl_down(r, off);
            if (tid == 0) atomicAdd(&sum_probs[l * 64 + img * 8 + e], r);
        }
    }
}

// ---------- scatter: counting-sort tokens into contiguous per-expert slot ranges
__global__ __launch_bounds__(256) void scatter_kernel(
    const uint* __restrict__ top2e, const float* __restrict__ top2w,
    const int* __restrict__ counts, int* __restrict__ cursors,
    int* __restrict__ btok, float* __restrict__ bw, int* __restrict__ slotAB, int l)
{
    const int t = blockIdx.x * 256 + threadIdx.x;
    const int lane = threadIdx.x & 63;
    int offs[8];
    {
        int acc0 = 0;
#pragma unroll
        for (int e = 0; e < 8; ++e) { offs[e] = acc0; acc0 += counts[l * 8 + e]; }
    }
    uint pe = top2e[t];
    for (int slot = 0; slot < 2; ++slot) {
        int esel = slot ? (int)((pe >> 8) & 255u) : (int)(pe & 255u);
        float wsel = top2w[2 * t + slot];
#pragma unroll
        for (int e = 0; e < 8; ++e) {
            unsigned long long m = __ballot(esel == e);
            int pc = __popcll(m);
            if (pc) {
                int leader = __ffsll(m) - 1;
                int basep = 0;
                if (lane == leader) basep = atomicAdd(&cursors[l * 8 + e], pc);
                basep = __shfl(basep, leader);
                if (esel == e) {
                    int pos = basep + __popcll(m & ((1ull << lane) - 1ull));
                    int sidx = offs[e] + pos;
                    btok[sidx] = t;
                    bw[sidx] = wsel;
                    slotAB[2 * t + slot] = sidx;
                }
            }
        }
    }
}

// ---------- grouped expert MLP (bf16 MFMA), writes w*(h2+b2) to buf[slot] (bf16)
__global__ __launch_bounds__(256) void expert_mfma(
    const short* __restrict__ Hb, short* __restrict__ buf,
    const int* __restrict__ counts, const int* __restrict__ btok, const float* __restrict__ bw,
    const short* __restrict__ ew1t, const float* __restrict__ eb1,
    const short* __restrict__ ew2t, const float* __restrict__ eb2, int l)
{
    const int e = blockIdx.y;
    int off = 0, cnt = 0;
#pragma unroll
    for (int i = 0; i < 8; ++i) {
        int c = counts[l * 8 + i];
        if (i < e) off += c;
        if (i == e) cnt = c;
    }
    const int base = blockIdx.x * 64;
    if (base >= cnt) return;

    __shared__ __align__(16) short As[64 * 32];
    __shared__ __align__(16) short Bs1[64 * 32];
    __shared__ __align__(16) short h1s[64 * 64];
    __shared__ __align__(16) short Bs2[128 * 64];
    __shared__ int tkS[64];
    __shared__ float wtS[64];

    const int tid = threadIdx.x;
    if (tid < 64) {
        bool valid = (base + tid) < cnt;
        tkS[tid] = valid ? btok[off + base + tid] : 0;
        wtS[tid] = valid ? bw[off + base + tid] : 0.0f;
    }
    __syncthreads();

    const int w = tid >> 6, lane = tid & 63;
    const int quad = lane >> 4, l15 = lane & 15;
    const int le = l * 8 + e;

    // phase 1: h1[64 tok][64 bn] = relu(Hb_rows @ W1 + b1)
    floatx4 acc1[4];
#pragma unroll
    for (int i = 0; i < 4; ++i) acc1[i] = 0.0f;

    const short* ap = Hb + (long)tkS[tid >> 2] * DM + (tid & 3) * 8;
    const short* bp = ew1t + ((long)le * 64 + (tid >> 2)) * DM + (tid & 3) * 8;
    short* asd = As + tid * 8;
    short* bsd = Bs1 + tid * 8;

    for (int k0 = 0; k0 < DM; k0 += 32) {
        __syncthreads();
        ASYNC16(ap + k0, asd);
        ASYNC16(bp + k0, bsd);
        __syncthreads();
        bf16x8 bfw = *(const bf16x8*)&Bs1[(w * 16 + l15) * 32 + quad * 8];
#pragma unroll
        for (int i = 0; i < 4; ++i) {
            bf16x8 af = *(const bf16x8*)&As[(i * 16 + l15) * 32 + quad * 8];
            acc1[i] = __builtin_amdgcn_mfma_f32_16x16x32_bf16(af, bfw, acc1[i], 0, 0, 0);
        }
    }
    {
        float b1v = eb1[le * BN + w * 16 + l15];
#pragma unroll
        for (int i = 0; i < 4; ++i)
#pragma unroll
            for (int r = 0; r < 4; ++r)
                h1s[(i * 16 + quad * 4 + r) * 64 + w * 16 + l15] =
                    f2bf(fmaxf(acc1[i][r] + b1v, 0.0f));
    }
    __syncthreads();

    // phase 2: out^T tiles; hoisted h1 fragments (B-operand role)
    bf16x8 a2[4][2];
    float wtv[4];
#pragma unroll
    for (int tj = 0; tj < 4; ++tj) {
        wtv[tj] = wtS[tj * 16 + l15];
#pragma unroll
        for (int kk = 0; kk < 2; ++kk)
            a2[tj][kk] = *(const bf16x8*)&h1s[(tj * 16 + l15) * 64 + kk * 32 + quad * 8];
    }
    const long b2w = (long)le * DM * 64;   // ew2t[le][n][k=64]

    for (int c8 = 0; c8 < 8; ++c8) {
        const int nc0 = c8 * 128;
        __syncthreads();
#pragma unroll
        for (int rr = 0; rr < 4; ++rr) {
            int c = tid + 256 * rr;
            ASYNC16(ew2t + b2w + (long)(nc0 + (c >> 3)) * 64 + (c & 7) * 8, Bs2 + c * 8);
        }
        __syncthreads();
        floatx4 acc2[2][4];
#pragma unroll
        for (int nj = 0; nj < 2; ++nj)
#pragma unroll
            for (int tj = 0; tj < 4; ++tj) acc2[nj][tj] = 0.0f;
#pragma unroll
        for (int kk = 0; kk < 2; ++kk) {
#pragma unroll
            for (int nj = 0; nj < 2; ++nj) {
                bf16x8 bf2 = *(const bf16x8*)&Bs2[(w * 32 + nj * 16 + l15) * 64 + kk * 32 + quad * 8];
#pragma unroll
                for (int tj = 0; tj < 4; ++tj)
                    acc2[nj][tj] = __builtin_amdgcn_mfma_f32_16x16x32_bf16(bf2, a2[tj][kk], acc2[nj][tj], 0, 0, 0);
            }
        }
        // epilogue: D^T -> lane holds 4 consecutive n for one token
#pragma unroll
        for (int nj = 0; nj < 2; ++nj) {
            int nb = nc0 + w * 32 + nj * 16 + quad * 4;
            float4 b2v = *(const float4*)&eb2[le * DM + nb];
#pragma unroll
            for (int tj = 0; tj < 4; ++tj) {
                int tok = tj * 16 + l15;
                if (base + tok < cnt) {
                    float wt = wtv[tj];
                    short4 pk;
                    pk.x = f2bf(wt * (acc2[nj][tj][0] + b2v.x));
                    pk.y = f2bf(wt * (acc2[nj][tj][1] + b2v.y));
                    pk.z = f2bf(wt * (acc2[nj][tj][2] + b2v.z));
                    pk.w = f2bf(wt * (acc2[nj][tj][3] + b2v.w));
                    *(short4*)(buf + (long)(off + base + tok) * DM + nb) = pk;
                }
            }
        }
    }
}

// ---------- combine: Hb[t] += buf[slotA[t]] + buf[slotB[t]]  (f32 math, bf16 store)
__global__ __launch_bounds__(256) void combine_kernel(
    short* __restrict__ Hb, const short* __restrict__ buf, const int* __restrict__ slotAB)
{
    const int t = blockIdx.x;
    const int d4 = threadIdx.x * 4;
    const int sA = slotAB[2 * t], sB = slotAB[2 * t + 1];
    short4 h4 = *(const short4*)&Hb[(long)t * DM + d4];
    short4 a4 = *(const short4*)&buf[(long)sA * DM + d4];
    short4 b4 = *(const short4*)&buf[(long)sB * DM + d4];
    h4.x = f2bf(bf2f(h4.x) + bf2f(a4.x) + bf2f(b4.x));
    h4.y = f2bf(bf2f(h4.y) + bf2f(a4.y) + bf2f(b4.y));
    h4.z = f2bf(bf2f(h4.z) + bf2f(a4.z) + bf2f(b4.z));
    h4.w = f2bf(bf2f(h4.w) + bf2f(a4.w) + bf2f(b4.w));
    *(short4*)&Hb[(long)t * DM + d4] = h4;
}

// ---------- vision_proj (unchanged, f32)
__global__ __launch_bounds__(256) void vproj_kernel(
    const float* __restrict__ pooled, const float* __restrict__ w_out,
    const float* __restrict__ b_out, float* __restrict__ outp)
{
    __shared__ float ps[8 * 128];
    const int tid = threadIdx.x;
    const int n = blockIdx.x * 256 + tid;
    const int d0 = blockIdx.y * 128;
#pragma unroll
    for (int i = 0; i < 4; ++i) {
        int idx = tid + i * 256;
        ps[idx] = pooled[(idx >> 7) * DM + d0 + (idx & 127)];
    }
    __syncthreads();
    float acc[8];
    float binit = (blockIdx.y == 0) ? b_out[n] : 0.0f;
#pragma unroll
    for (int img = 0; img < 8; ++img) acc[img] = binit;
    for (int d = 0; d < 128; ++d) {
        float wv = w_out[(long)(d0 + d) * DOUT + n];
#pragma unroll
        for (int img = 0; img < 8; ++img) acc[img] += ps[img * 128 + d] * wv;
    }
#pragma unroll
    for (int img = 0; img < 8; ++img) atomicAdd(&outp[img * DOUT + n], acc[img]);
}

// ---------- aux
__global__ __launch_bounds__(64) void aux_kernel(
    const float* __restrict__ sum_probs, const float* __restrict__ mask_cnt,
    float* __restrict__ outp)
{
    const int tid = threadIdx.x;
    float v = 0.0f;
    if (tid < 32) {
        float s = 0.0f;
#pragma unroll
        for (int e = 0; e < 8; ++e) s += sum_probs[tid * 8 + e] * mask_cnt[tid * 8 + e];
        v = s * (8.0f / (4096.0f * 4096.0f));
    }
    for (int off = 32; off > 0; off >>= 1) v += __shfl_down(v, off);
    if (tid == 0) outp[0] = v;
}

extern "C" void kernel_launch(void* const* d_in, const int* in_sizes, int n_in,
                              void* d_out, int out_size, void* d_ws, size_t ws_size,
                              hipStream_t stream) {
    const float* X       = (const float*)d_in[0];
    const float* w_in    = (const float*)d_in[2];
    const float* w_sc1   = (const float*)d_in[3];
    const float* b_sc1   = (const float*)d_in[4];
    const float* w_sc2   = (const float*)d_in[5];
    const float* b_sc2   = (const float*)d_in[6];
    const float* w_rimg  = (const float*)d_in[7];
    const float* w_rskin = (const float*)d_in[8];
    const float* ew1     = (const float*)d_in[9];
    const float* eb1     = (const float*)d_in[10];
    const float* ew2     = (const float*)d_in[11];
    const float* eb2     = (const float*)d_in[12];
    const float* w_out   = (const float*)d_in[13];
    const float* b_out   = (const float*)d_in[14];

    float* out = (float*)d_out;
    char* ws = (char*)d_ws;

    short* Hb     = (short*)(ws + OFF_HB);
    short* buf    = (short*)(ws + OFF_BUF);
    short* Xb     = (short*)(ws + OFF_BUF);     // alias: consumed before buf is used
    short* Wbt    = (short*)(ws + OFF_WBT);
    short* ew1t   = (short*)(ws + OFF_EW1T);
    short* ew2t   = (short*)(ws + OFF_EW2T);
    int*   btok   = (int*)(ws + OFF_BTOK);
    float* bwp    = (float*)(ws + OFF_BW);
    int*   slotAB = (int*)(ws + OFF_SLOT);
    uint*  top2e  = (uint*)(ws + OFF_T2E);
    float* top2w  = (float*)(ws + OFF_T2W);
    int*   counts    = (int*)(ws + OFF_Z);
    int*   cursors   = (int*)(ws + OFF_Z + 128);
    float* sum_probs = (float*)(ws + OFF_Z + 256);
    float* mask_cnt  = (float*)(ws + OFF_Z + 1280);
    float* g         = (float*)(ws + OFF_Z + 2304);
    float* rb        = (float*)(ws + OFF_Z + 2304 + 32768 - 1024);  // reuse tail of g region? NO:
    // rb gets its own space right after Z
    rb = (float*)(ws + OFF_Z + Z_BYTES);

    hipMemsetAsync(d_out, 0, (size_t)out_size * sizeof(float), stream);
    hipMemsetAsync(ws + OFF_Z, 0, Z_BYTES, stream);

    dim3 b256(256);
    convx_kernel<<<TT, b256, 0, stream>>>(X, Xb);
    transp_kernel<<<dim3(19, 16, 1), b256, 0, stream>>>(w_in, Wbt, DIN, DM, KP);
    transp_kernel<<<dim3(16, 1, 32), b256, 0, stream>>>(ew1, ew1t, DM, BN, DM);
    transp_kernel<<<dim3(1, 16, 32), b256, 0, stream>>>(ew2, ew2t, BN, DM, BN);
    gemm_in_mfma<<<dim3(8, 256), b256, 0, stream>>>(Xb, Wbt, Hb);
    colmean_kernel<<<dim3(4, 8, 16), b256, 0, stream>>>(Hb, g);
    skin_kernel<<<1, b256, 0, stream>>>(g, w_sc1, b_sc1, w_sc2, b_sc2, w_rskin,
                                        out + 40961, rb);
    for (int l = 0; l < NL; ++l) {
        router_kernel<<<512, b256, 0, stream>>>(Hb, w_rimg, rb, top2e, top2w,
                                                counts, sum_probs, mask_cnt, l);
        scatter_kernel<<<128, b256, 0, stream>>>(top2e, top2w, counts, cursors,
                                                 btok, bwp, slotAB, l);
        expert_mfma<<<dim3(512, 8), b256, 0, stream>>>(Hb, buf, counts, btok, bwp,
                                                       ew1t, eb1, ew2t, eb2, l);
        combine_kernel<<<TT, b256, 0, stream>>>(Hb, buf, slotAB);
    }
    colmean_kernel<<<dim3(4, 8, 16), b256, 0, stream>>>(Hb, out);
    vproj_kernel<<<dim3(16, 8), b256, 0, stream>>>(out, w_out, b_out, out + 8192);
    aux_kernel<<<1, 64, 0, stream>>>(sum_probs, mask_cnt, out + 40960);
}

// Round 3
// 1690.613 us; speedup vs baseline: 3.6965x; 1.1644x over previous
//
#include <hip/hip_runtime.h>
#include <math.h>

#define TPI  4096
#define TT   32768
#define DIN  1176
#define KP   1184
#define DM   1024
#define NE   8
#define BN   64
#define NL   4
#define DOUT 4096

typedef __attribute__((ext_vector_type(4))) float floatx4;
typedef __attribute__((ext_vector_type(8))) short bf16x8;
typedef unsigned int uint;

__device__ inline short f2bf(float x) {
    unsigned u = __float_as_uint(x);
    u += 0x7fffu + ((u >> 16) & 1u);
    return (short)(u >> 16);
}
__device__ inline float bf2f(short h) {
    return __uint_as_float(((unsigned)(unsigned short)h) << 16);
}

#define GLP(p) ((const __attribute__((address_space(1))) void*)(p))
#define LDSP(p) ((__attribute__((address_space(3))) void*)(p))
#define ASYNC16(g, s) __builtin_amdgcn_global_load_lds(GLP(g), LDSP(s), 16, 0, 0)

// ws layout (bytes)
#define OFF_H0    0ul
#define OFF_H1    67108864ul
#define OFF_XB    134217728ul
#define OFF_WBT   211812352ul
#define OFF_E1T   214237184ul
#define OFF_E2T   218431488ul
#define OFF_BTOK  222625792ul
#define OFF_BW1   222756864ul
#define OFF_BW2   222887936ul
#define OFF_T2E   223019008ul
#define OFF_T2W   223150080ul
#define OFF_WQ    223412224ul
#define OFF_Z     223416320ul
#define Z_BYTES   38976ul
#define OFF_RB    223455296ul
// Z sub-offsets (bytes from OFF_Z)
//   0: counts_pair i32[256]   1024: cursors i32[256]   2048: nwork i32[16]
//   2112: sum_probs f[256]    3136: mask_cnt f[256]    4160: g f[8192]
//   36928: hsg f[512]

// ---------- convert X (f32) -> Xb (bf16, KP-padded), vectorized
__global__ __launch_bounds__(256) void convx_kernel(
    const float* __restrict__ X, short* __restrict__ Xb)
{
    const long row = blockIdx.x;
    const float* src = X + row * (long)DIN;
    short* dst = Xb + row * (long)KP;
    for (int i = threadIdx.x; i < 296; i += 256) {
        short4 s;
        if (i < 294) {
            float4 v = *(const float4*)(src + i * 4);
            s.x = f2bf(v.x); s.y = f2bf(v.y); s.z = f2bf(v.z); s.w = f2bf(v.w);
        } else {
            s.x = 0; s.y = 0; s.z = 0; s.w = 0;
        }
        *(short4*)(dst + i * 4) = s;
    }
}

// ---------- generic transpose: dst[n][k] (row len DK) = src[k][n]
__global__ __launch_bounds__(256) void transp_kernel(
    const float* __restrict__ src, short* __restrict__ dst, int RS, int CS, int DK)
{
    __shared__ float tb[64][65];
    const int kt = blockIdx.x * 64, nt = blockIdx.y * 64;
    const long sb = (long)blockIdx.z * RS * CS;
    const long db = (long)blockIdx.z * CS * DK;
    const int rr = threadIdx.x >> 6, cc = threadIdx.x & 63;
#pragma unroll
    for (int i = 0; i < 16; ++i) {
        int r = i * 4 + rr;
        int k = kt + r, n = nt + cc;
        tb[r][cc] = (k < RS && n < CS) ? src[sb + (long)k * CS + n] : 0.0f;
    }
    __syncthreads();
#pragma unroll
    for (int i = 0; i < 16; ++i) {
        int r = i * 4 + rr;
        int n = nt + r, k = kt + cc;
        if (n < CS && k < DK) dst[db + (long)n * DK + k] = f2bf(tb[cc][r]);
    }
}

// ---------- in_proj MFMA GEMM (x = m fastest for XCD locality)
__global__ __launch_bounds__(256) void gemm_in_mfma(
    const short* __restrict__ Xb, const short* __restrict__ Wbt, short* __restrict__ Hb)
{
    __shared__ __align__(16) short As[128 * 32];
    __shared__ __align__(16) short Bs[128 * 32];
    const int tid = threadIdx.x;
    const int m0 = blockIdx.x * 128, n0 = blockIdx.y * 128;
    const int w = tid >> 6, lane = tid & 63;
    const int quad = lane >> 4, l15 = lane & 15;
    const int wm = (w >> 1) * 64, wn = (w & 1) * 64;

    floatx4 acc[4][4];
#pragma unroll
    for (int i = 0; i < 4; ++i)
#pragma unroll
        for (int j = 0; j < 4; ++j) acc[i][j] = 0.0f;

    const int r0 = tid >> 2, kof = (tid & 3) * 8;
    const int r1 = (tid + 256) >> 2;
    const short* a0p = Xb + (long)(m0 + r0) * KP + kof;
    const short* a1p = Xb + (long)(m0 + r1) * KP + kof;
    const short* b0p = Wbt + (long)(n0 + r0) * KP + kof;
    const short* b1p = Wbt + (long)(n0 + r1) * KP + kof;
    short* as0 = As + tid * 8;
    short* as1 = As + (tid + 256) * 8;
    short* bs0 = Bs + tid * 8;
    short* bs1 = Bs + (tid + 256) * 8;

    for (int k0 = 0; k0 < KP; k0 += 32) {
        __syncthreads();
        ASYNC16(a0p + k0, as0);
        ASYNC16(a1p + k0, as1);
        ASYNC16(b0p + k0, bs0);
        ASYNC16(b1p + k0, bs1);
        __syncthreads();
        bf16x8 af[4], bfr[4];
#pragma unroll
        for (int i = 0; i < 4; ++i)
            af[i] = *(const bf16x8*)&As[(wm + i * 16 + l15) * 32 + quad * 8];
#pragma unroll
        for (int j = 0; j < 4; ++j)
            bfr[j] = *(const bf16x8*)&Bs[(wn + j * 16 + l15) * 32 + quad * 8];
#pragma unroll
        for (int i = 0; i < 4; ++i)
#pragma unroll
            for (int j = 0; j < 4; ++j)
                acc[i][j] = __builtin_amdgcn_mfma_f32_16x16x32_bf16(af[i], bfr[j], acc[i][j], 0, 0, 0);
    }
#pragma unroll
    for (int i = 0; i < 4; ++i)
#pragma unroll
        for (int j = 0; j < 4; ++j)
#pragma unroll
            for (int r = 0; r < 4; ++r)
                Hb[(long)(m0 + wm + i * 16 + quad * 4 + r) * DM + n0 + wn + j * 16 + l15] =
                    f2bf(acc[i][j][r]);
}

// ---------- column mean of Hb into f32 dest
__global__ __launch_bounds__(256) void colmean_kernel(
    const short* __restrict__ Hb, float* __restrict__ outp)
{
    const int col = blockIdx.x * 256 + threadIdx.x;
    const int img = blockIdx.y;
    const int t0 = blockIdx.z * 256;
    const short* p = Hb + ((long)img * TPI + t0) * DM + col;
    float s = 0.0f;
#pragma unroll 8
    for (int t = 0; t < 256; ++t) s += bf2f(p[(long)t * DM]);
    atomicAdd(&outp[img * DM + col], s * (1.0f / 4096.0f));
}

// ---------- skin stage 1: hsg[img][64] = relu(g[img] @ w_sc1 + b_sc1), one block per img
__global__ __launch_bounds__(256) void skin1_kernel(
    const float* __restrict__ g, const float* __restrict__ w_sc1,
    const float* __restrict__ b_sc1, float* __restrict__ hsg)
{
    __shared__ float red[4][64];
    const int img = blockIdx.x;
    const int part = threadIdx.x >> 6, c = threadIdx.x & 63;
    float s = 0.0f;
    for (int i = 0; i < 256; ++i) {
        int d = part * 256 + i;
        s += g[img * DM + d] * w_sc1[d * 64 + c];
    }
    red[part][c] = s;
    __syncthreads();
    if (part == 0) {
        float v = red[0][c] + red[1][c] + red[2][c] + red[3][c] + b_sc1[c];
        hsg[img * 64 + c] = fmaxf(v, 0.0f);
    }
}

// ---------- skin stage 2: logits, softmax, rb
__global__ __launch_bounds__(256) void skin2_kernel(
    const float* __restrict__ hsg, const float* __restrict__ w_sc2, const float* __restrict__ b_sc2,
    const float* __restrict__ w_rskin, float* __restrict__ skin_logits_out, float* __restrict__ rb)
{
    __shared__ float l3[24];
    __shared__ float sp[24];
    const int tid = threadIdx.x;
    if (tid < 24) {
        int img = tid / 3, j = tid % 3;
        float s = b_sc2[j];
        for (int c = 0; c < 64; ++c) s += hsg[img * 64 + c] * w_sc2[c * 3 + j];
        l3[tid] = s;
        skin_logits_out[tid] = s;
    }
    __syncthreads();
    if (tid < 8) {
        float v0 = l3[tid * 3], v1 = l3[tid * 3 + 1], v2 = l3[tid * 3 + 2];
        float m = fmaxf(v0, fmaxf(v1, v2));
        float e0 = expf(v0 - m), e1 = expf(v1 - m), e2 = expf(v2 - m);
        float inv = 1.0f / (e0 + e1 + e2);
        sp[tid * 3] = e0 * inv; sp[tid * 3 + 1] = e1 * inv; sp[tid * 3 + 2] = e2 * inv;
    }
    __syncthreads();
    {
        int l = tid >> 6, img = (tid >> 3) & 7, e = tid & 7;
        float s = 0.0f;
#pragma unroll
        for (int c = 0; c < 3; ++c) s += sp[img * 3 + c] * w_rskin[(l * 3 + c) * 8 + e];
        rb[tid] = s;
    }
}

// ---------- router: logits -> softmax -> top2 + pair counts + aux
__global__ __launch_bounds__(256) void router_kernel(
    const short* __restrict__ Hb, const float* __restrict__ w_rimg, const float* __restrict__ rb,
    uint* __restrict__ top2e, float* __restrict__ top2w, int* __restrict__ counts_pair,
    float* __restrict__ sum_probs, float* __restrict__ mask_cnt, int l)
{
    __shared__ float wl[DM * NE];
    __shared__ __align__(16) short hs[64 * 64];
    __shared__ float lgS[64 * 8];
    const int tid = threadIdx.x;
    const int tok0 = blockIdx.x * 64;
    const int img = tok0 >> 12;

    const float* wr = w_rimg + (long)l * DM * NE;
#pragma unroll
    for (int i = 0; i < 32; ++i) wl[tid + 256 * i] = wr[tid + 256 * i];

    const int tok = tid & 63, ep = tid >> 6, e0 = ep * 2;
    const int c0 = tid, c1 = tid + 256;
    const short* g0 = Hb + (long)(tok0 + (c0 >> 3)) * DM + (c0 & 7) * 8;
    const short* g1 = Hb + (long)(tok0 + (c1 >> 3)) * DM + (c1 & 7) * 8;
    short* s0 = hs + c0 * 8;
    short* s1 = hs + c1 * 8;

    float a0 = 0.0f, a1 = 0.0f;
    for (int ds = 0; ds < 16; ++ds) {
        __syncthreads();
        ASYNC16(g0 + ds * 64, s0);
        ASYNC16(g1 + ds * 64, s1);
        __syncthreads();
#pragma unroll
        for (int d8 = 0; d8 < 8; ++d8) {
            bf16x8 h8 = *(const bf16x8*)&hs[tok * 64 + d8 * 8];
#pragma unroll
            for (int jj = 0; jj < 8; ++jj) {
                float hv = bf2f(h8[jj]);
                int gd = ds * 64 + d8 * 8 + jj;
                a0 += hv * wl[gd * 8 + e0];
                a1 += hv * wl[gd * 8 + e0 + 1];
            }
        }
    }
    lgS[tok * 8 + e0] = a0;
    lgS[tok * 8 + e0 + 1] = a1;
    __syncthreads();

    if (tid < 64) {
        const int token = tok0 + tid;
        float p[8];
        float mx = -1e30f;
#pragma unroll
        for (int e = 0; e < 8; ++e) {
            float v = lgS[tid * 8 + e] + rb[l * 64 + img * 8 + e];
            p[e] = v; mx = fmaxf(mx, v);
        }
        float s = 0.0f;
#pragma unroll
        for (int e = 0; e < 8; ++e) { p[e] = expf(p[e] - mx); s += p[e]; }
        float inv = 1.0f / s;
#pragma unroll
        for (int e = 0; e < 8; ++e) p[e] *= inv;

        int i1 = 0; float b1v = p[0];
#pragma unroll
        for (int e = 1; e < 8; ++e) if (p[e] > b1v) { b1v = p[e]; i1 = e; }
        int i2 = -1; float b2v = -1.0f;
#pragma unroll
        for (int e = 0; e < 8; ++e) if (e != i1 && p[e] > b2v) { b2v = p[e]; i2 = e; }
        float den = b1v + b2v + 1e-6f;
        top2e[token] = (uint)i1 | ((uint)i2 << 8);
        top2w[2 * token] = b1v / den;
        top2w[2 * token + 1] = b2v / den;

        atomicAdd(&counts_pair[l * 64 + i1 * 8 + i2], 1);

        for (int slot = 0; slot < 2; ++slot) {
            int esel = slot ? i2 : i1;
#pragma unroll
            for (int e = 0; e < 8; ++e) {
                unsigned long long m = __ballot(esel == e);
                int pc = __popcll(m);
                if (pc && tid == (__ffsll(m) - 1))
                    atomicAdd(&mask_cnt[l * 64 + img * 8 + e], (float)pc);
            }
        }
#pragma unroll
        for (int e = 0; e < 8; ++e) {
            float r = p[e];
            for (int off = 32; off > 0; off >>= 1) r += __shfl_down(r, off);
            if (tid == 0) atomicAdd(&sum_probs[l * 64 + img * 8 + e], r);
        }
    }
}

// ---------- scatter by expert-pair into contiguous slot ranges
__global__ __launch_bounds__(256) void scatter_kernel(
    const uint* __restrict__ top2e, const float* __restrict__ top2w,
    const int* __restrict__ counts_pair, int* __restrict__ cursors,
    int* __restrict__ btok, float* __restrict__ bw1, float* __restrict__ bw2, int l)
{
    const int t = blockIdx.x * 256 + threadIdx.x;
    const int lane = threadIdx.x & 63;
    uint pe = top2e[t];
    int p = (int)(pe & 255u) * 8 + (int)((pe >> 8) & 255u);
    float w1 = top2w[2 * t], w2 = top2w[2 * t + 1];
    int myoff = 0;
    for (int q = 0; q < 64; ++q) {
        int c = counts_pair[l * 64 + q];
        if (q < p) myoff += c;
    }
    unsigned long long rem = __ballot(true);
    while (rem) {
        int leader = __ffsll(rem) - 1;
        int pv = __shfl(p, leader);
        unsigned long long m = __ballot(p == pv);
        int basep = 0;
        if (lane == leader) basep = atomicAdd(&cursors[l * 64 + pv], __popcll(m));
        basep = __shfl(basep, leader);
        if (p == pv) {
            int pos = basep + __popcll(m & ((1ull << lane) - 1ull));
            int s = myoff + pos;
            btok[s] = t;
            bw1[s] = w1;
            bw2[s] = w2;
        }
        rem &= ~m;
    }
}

// ---------- build work queue: one entry per (pair, 64-token tile)
__global__ __launch_bounds__(64) void wq_kernel(
    const int* __restrict__ counts_pair, int* __restrict__ wq, int* __restrict__ nworkp, int l)
{
    const int p = threadIdx.x;
    int cnt = counts_pair[l * 64 + p];
    int nb = (cnt + 63) >> 6;
    int x = nb;
    for (int off = 1; off < 64; off <<= 1) {
        int y = __shfl_up(x, off);
        if (p >= off) x += y;
    }
    int start = x - nb;
    for (int i = 0; i < nb; ++i) wq[start + i] = p | ((i * 64) << 6);
    if (p == 63) nworkp[0] = x;
}

// ---------- fused pair-expert MLP: Hout[t] = Hin[t] + w1*mlp_a(Hin[t]) + w2*mlp_b(Hin[t])
__global__ __launch_bounds__(256) void expert_pair(
    const short* __restrict__ Hin, short* __restrict__ Hout,
    const int* __restrict__ counts_pair, const int* __restrict__ btok,
    const float* __restrict__ bw1, const float* __restrict__ bw2,
    const short* __restrict__ ew1t, const float* __restrict__ eb1,
    const short* __restrict__ ew2t, const float* __restrict__ eb2,
    const int* __restrict__ wq, const int* __restrict__ nworkp, int l)
{
    __shared__ __align__(16) short As[64 * 32];
    __shared__ __align__(16) short h1a[64 * 72];
    __shared__ __align__(16) short h1b[64 * 72];
    __shared__ int tkS[64];
    __shared__ float w1S[64], w2S[64];

    const int tid = threadIdx.x;
    const int w = tid >> 6, lane = tid & 63;
    const int quad = lane >> 4, l15 = lane & 15;
    const int nwork = nworkp[0];

    for (int wi = blockIdx.x; wi < nwork; wi += gridDim.x) {
        const int item = wq[wi];
        const int p = item & 63, base = item >> 6;
        const int ea = p >> 3, eb = p & 7;
        int off = 0, cnt = 0;
        for (int q = 0; q < 64; ++q) {
            int c = counts_pair[l * 64 + q];
            if (q < p) off += c;
            if (q == p) cnt = c;
        }
        __syncthreads();
        if (tid < 64) {
            bool valid = (base + tid) < cnt;
            int s = off + base + tid;
            tkS[tid] = valid ? btok[s] : 0;
            w1S[tid] = valid ? bw1[s] : 0.0f;
            w2S[tid] = valid ? bw2[s] : 0.0f;
        }
        __syncthreads();
        const int lea = l * 8 + ea, leb = l * 8 + eb;

        // phase 1: h1a/h1b[64 tok][64 bn]
        floatx4 acc1a[4], acc1b[4];
#pragma unroll
        for (int i = 0; i < 4; ++i) { acc1a[i] = 0.0f; acc1b[i] = 0.0f; }

        const short* ap = Hin + (long)tkS[tid >> 2] * DM + (tid & 3) * 8;
        const short* w1ap = ew1t + ((long)lea * 64 + w * 16 + l15) * DM + quad * 8;
        const short* w1bp = ew1t + ((long)leb * 64 + w * 16 + l15) * DM + quad * 8;
        short* asd = As + tid * 8;

        for (int k0 = 0; k0 < DM; k0 += 32) {
            __syncthreads();
            ASYNC16(ap + k0, asd);
            __syncthreads();
            bf16x8 ba = *(const bf16x8*)(w1ap + k0);   // direct global (L2-hot weights)
            bf16x8 bb = *(const bf16x8*)(w1bp + k0);
#pragma unroll
            for (int i = 0; i < 4; ++i) {
                bf16x8 af = *(const bf16x8*)&As[(i * 16 + l15) * 32 + quad * 8];
                acc1a[i] = __builtin_amdgcn_mfma_f32_16x16x32_bf16(af, ba, acc1a[i], 0, 0, 0);
                acc1b[i] = __builtin_amdgcn_mfma_f32_16x16x32_bf16(af, bb, acc1b[i], 0, 0, 0);
            }
        }
        {
            float b1av = eb1[lea * BN + w * 16 + l15];
            float b1bv = eb1[leb * BN + w * 16 + l15];
#pragma unroll
            for (int i = 0; i < 4; ++i)
#pragma unroll
                for (int r = 0; r < 4; ++r) {
                    h1a[(i * 16 + quad * 4 + r) * 72 + w * 16 + l15] =
                        f2bf(fmaxf(acc1a[i][r] + b1av, 0.0f));
                    h1b[(i * 16 + quad * 4 + r) * 72 + w * 16 + l15] =
                        f2bf(fmaxf(acc1b[i][r] + b1bv, 0.0f));
                }
        }
        __syncthreads();

        // phase 2: Dt[n][tok] for n-slices of 64; W2 frags direct from global (L2)
        const short* w2ap = ew2t + ((long)lea * DM + w * 16 + l15) * 64 + quad * 8;
        const short* w2bp = ew2t + ((long)leb * DM + w * 16 + l15) * 64 + quad * 8;
        for (int n0 = 0; n0 < DM; n0 += 64) {
            floatx4 a2a[4], a2b[4];
#pragma unroll
            for (int tj = 0; tj < 4; ++tj) { a2a[tj] = 0.0f; a2b[tj] = 0.0f; }
#pragma unroll
            for (int kk = 0; kk < 2; ++kk) {
                bf16x8 wa = *(const bf16x8*)(w2ap + (long)n0 * 64 + kk * 32);
                bf16x8 wb = *(const bf16x8*)(w2bp + (long)n0 * 64 + kk * 32);
#pragma unroll
                for (int tj = 0; tj < 4; ++tj) {
                    bf16x8 ha = *(const bf16x8*)&h1a[(tj * 16 + l15) * 72 + kk * 32 + quad * 8];
                    bf16x8 hb = *(const bf16x8*)&h1b[(tj * 16 + l15) * 72 + kk * 32 + quad * 8];
                    a2a[tj] = __builtin_amdgcn_mfma_f32_16x16x32_bf16(wa, ha, a2a[tj], 0, 0, 0);
                    a2b[tj] = __builtin_amdgcn_mfma_f32_16x16x32_bf16(wb, hb, a2b[tj], 0, 0, 0);
                }
            }
            const int nb = n0 + w * 16 + quad * 4;
            float4 b2av = *(const float4*)&eb2[lea * DM + nb];
            float4 b2bv = *(const float4*)&eb2[leb * DM + nb];
#pragma unroll
            for (int tj = 0; tj < 4; ++tj) {
                int tk = tj * 16 + l15;
                if (base + tk < cnt) {
                    int t = tkS[tk];
                    float w1 = w1S[tk], w2 = w2S[tk];
                    short4 hres = *(const short4*)&Hin[(long)t * DM + nb];
                    short4 o;
                    o.x = f2bf(bf2f(hres.x) + w1 * (a2a[tj][0] + b2av.x) + w2 * (a2b[tj][0] + b2bv.x));
                    o.y = f2bf(bf2f(hres.y) + w1 * (a2a[tj][1] + b2av.y) + w2 * (a2b[tj][1] + b2bv.y));
                    o.z = f2bf(bf2f(hres.z) + w1 * (a2a[tj][2] + b2av.z) + w2 * (a2b[tj][2] + b2bv.z));
                    o.w = f2bf(bf2f(hres.w) + w1 * (a2a[tj][3] + b2av.w) + w2 * (a2b[tj][3] + b2bv.w));
                    *(short4*)&Hout[(long)t * DM + nb] = o;
                }
            }
        }
    }
}

// ---------- vision_proj
__global__ __launch_bounds__(256) void vproj_kernel(
    const float* __restrict__ pooled, const float* __restrict__ w_out,
    const float* __restrict__ b_out, float* __restrict__ outp)
{
    __shared__ float ps[8 * 128];
    const int tid = threadIdx.x;
    const int n = blockIdx.x * 256 + tid;
    const int d0 = blockIdx.y * 128;
#pragma unroll
    for (int i = 0; i < 4; ++i) {
        int idx = tid + i * 256;
        ps[idx] = pooled[(idx >> 7) * DM + d0 + (idx & 127)];
    }
    __syncthreads();
    float acc[8];
    float binit = (blockIdx.y == 0) ? b_out[n] : 0.0f;
#pragma unroll
    for (int img = 0; img < 8; ++img) acc[img] = binit;
    for (int d = 0; d < 128; ++d) {
        float wv = w_out[(long)(d0 + d) * DOUT + n];
#pragma unroll
        for (int img = 0; img < 8; ++img) acc[img] += ps[img * 128 + d] * wv;
    }
#pragma unroll
    for (int img = 0; img < 8; ++img) atomicAdd(&outp[img * DOUT + n], acc[img]);
}

// ---------- aux
__global__ __launch_bounds__(64) void aux_kernel(
    const float* __restrict__ sum_probs, const float* __restrict__ mask_cnt,
    float* __restrict__ outp)
{
    const int tid = threadIdx.x;
    float v = 0.0f;
    if (tid < 32) {
        float s = 0.0f;
#pragma unroll
        for (int e = 0; e < 8; ++e) s += sum_probs[tid * 8 + e] * mask_cnt[tid * 8 + e];
        v = s * (8.0f / (4096.0f * 4096.0f));
    }
    for (int off = 32; off > 0; off >>= 1) v += __shfl_down(v, off);
    if (tid == 0) outp[0] = v;
}

extern "C" void kernel_launch(void* const* d_in, const int* in_sizes, int n_in,
                              void* d_out, int out_size, void* d_ws, size_t ws_size,
                              hipStream_t stream) {
    const float* X       = (const float*)d_in[0];
    const float* w_in    = (const float*)d_in[2];
    const float* w_sc1   = (const float*)d_in[3];
    const float* b_sc1   = (const float*)d_in[4];
    const float* w_sc2   = (const float*)d_in[5];
    const float* b_sc2   = (const float*)d_in[6];
    const float* w_rimg  = (const float*)d_in[7];
    const float* w_rskin = (const float*)d_in[8];
    const float* ew1     = (const float*)d_in[9];
    const float* eb1     = (const float*)d_in[10];
    const float* ew2     = (const float*)d_in[11];
    const float* eb2     = (const float*)d_in[12];
    const float* w_out   = (const float*)d_in[13];
    const float* b_out   = (const float*)d_in[14];

    float* out = (float*)d_out;
    char* ws = (char*)d_ws;

    short* H0   = (short*)(ws + OFF_H0);
    short* H1   = (short*)(ws + OFF_H1);
    short* Xb   = (short*)(ws + OFF_XB);
    short* Wbt  = (short*)(ws + OFF_WBT);
    short* ew1t = (short*)(ws + OFF_E1T);
    short* ew2t = (short*)(ws + OFF_E2T);
    int*   btok = (int*)(ws + OFF_BTOK);
    float* bw1  = (float*)(ws + OFF_BW1);
    float* bw2  = (float*)(ws + OFF_BW2);
    uint*  top2e = (uint*)(ws + OFF_T2E);
    float* top2w = (float*)(ws + OFF_T2W);
    int*   wq    = (int*)(ws + OFF_WQ);
    int*   counts_pair = (int*)(ws + OFF_Z);
    int*   cursors     = (int*)(ws + OFF_Z + 1024);
    int*   nworkp      = (int*)(ws + OFF_Z + 2048);
    float* sum_probs   = (float*)(ws + OFF_Z + 2112);
    float* mask_cnt    = (float*)(ws + OFF_Z + 3136);
    float* g           = (float*)(ws + OFF_Z + 4160);
    float* hsg         = (float*)(ws + OFF_Z + 36928);
    float* rb          = (float*)(ws + OFF_RB);

    hipMemsetAsync(d_out, 0, (size_t)out_size * sizeof(float), stream);
    hipMemsetAsync(ws + OFF_Z, 0, Z_BYTES, stream);

    dim3 b256(256);
    convx_kernel<<<TT, b256, 0, stream>>>(X, Xb);
    transp_kernel<<<dim3(19, 16, 1), b256, 0, stream>>>(w_in, Wbt, DIN, DM, KP);
    transp_kernel<<<dim3(16, 1, 32), b256, 0, stream>>>(ew1, ew1t, DM, BN, DM);
    transp_kernel<<<dim3(1, 16, 32), b256, 0, stream>>>(ew2, ew2t, BN, DM, BN);
    gemm_in_mfma<<<dim3(256, 8), b256, 0, stream>>>(Xb, Wbt, H0);
    colmean_kernel<<<dim3(4, 8, 16), b256, 0, stream>>>(H0, g);
    skin1_kernel<<<8, b256, 0, stream>>>(g, w_sc1, b_sc1, hsg);
    skin2_kernel<<<1, b256, 0, stream>>>(hsg, w_sc2, b_sc2, w_rskin, out + 40961, rb);

    short* Hc = H0;
    short* Hn = H1;
    for (int l = 0; l < NL; ++l) {
        router_kernel<<<512, b256, 0, stream>>>(Hc, w_rimg, rb, top2e, top2w,
                                                counts_pair, sum_probs, mask_cnt, l);
        scatter_kernel<<<128, b256, 0, stream>>>(top2e, top2w, counts_pair, cursors,
                                                 btok, bw1, bw2, l);
        wq_kernel<<<1, 64, 0, stream>>>(counts_pair, wq, nworkp, l);
        expert_pair<<<640, b256, 0, stream>>>(Hc, Hn, counts_pair, btok, bw1, bw2,
                                              ew1t, eb1, ew2t, eb2, wq, nworkp, l);
        short* tmp = Hc; Hc = Hn; Hn = tmp;
    }
    colmean_kernel<<<dim3(4, 8, 16), b256, 0, stream>>>(Hc, out);
    vproj_kernel<<<dim3(16, 8), b256, 0, stream>>>(out, w_out, b_out, out + 8192);
    aux_kernel<<<1, 64, 0, stream>>>(sum_probs, mask_cnt, out + 40960);
}

// Round 4
// 1492.564 us; speedup vs baseline: 4.1870x; 1.1327x over previous
//
#include <hip/hip_runtime.h>
#include <math.h>

#define TPI  4096
#define TT   32768
#define DIN  1176
#define KP   1184
#define DM   1024
#define NE   8
#define BN   64
#define NL   4
#define DOUT 4096

typedef __attribute__((ext_vector_type(4))) float floatx4;
typedef __attribute__((ext_vector_type(8))) short bf16x8;
typedef unsigned int uint;

__device__ inline short f2bf(float x) {
    unsigned u = __float_as_uint(x);
    u += 0x7fffu + ((u >> 16) & 1u);
    return (short)(u >> 16);
}
__device__ inline float bf2f(short h) {
    return __uint_as_float(((unsigned)(unsigned short)h) << 16);
}

#define GLP(p) ((const __attribute__((address_space(1))) void*)(p))
#define LDSP(p) ((__attribute__((address_space(3))) void*)(p))
#define ASYNC16(g, s) __builtin_amdgcn_global_load_lds(GLP(g), LDSP(s), 16, 0, 0)

// ws layout (bytes)
#define OFF_H0    0ul
#define OFF_H1    67108864ul
#define OFF_XB    134217728ul
#define OFF_WBT   211812352ul
#define OFF_E1T   214237184ul
#define OFF_E2T   218431488ul
#define OFF_BTOK  222625792ul
#define OFF_BW1   222756864ul
#define OFF_BW2   222887936ul
#define OFF_T2E   223019008ul
#define OFF_T2W   223150080ul
#define OFF_WQ    223412224ul
#define OFF_Z     223416320ul
// Z sub-offsets (bytes): 0 counts_pair[256]i | 1024 cursors[256]i | 2048 nwork[16]i
//   2112 pair_off[64]i | 2368 sum_probs[256]f | 3392 mask_cnt[256]f | 4416 g[8192]f
//   37184 hsg[512]f
#define Z_BYTES   39232ul
#define OFF_RB    223455552ul
#define OFF_WRT   223456576ul   // bf16 [4][16][1024] = 131072 B

// ---------- convert X (f32) -> Xb (bf16, KP-padded)
__global__ __launch_bounds__(256) void convx_kernel(
    const float* __restrict__ X, short* __restrict__ Xb)
{
    const long row = blockIdx.x;
    const float* src = X + row * (long)DIN;
    short* dst = Xb + row * (long)KP;
    for (int i = threadIdx.x; i < 296; i += 256) {
        short4 s;
        if (i < 294) {
            float4 v = *(const float4*)(src + i * 4);
            s.x = f2bf(v.x); s.y = f2bf(v.y); s.z = f2bf(v.z); s.w = f2bf(v.w);
        } else {
            s.x = 0; s.y = 0; s.z = 0; s.w = 0;
        }
        *(short4*)(dst + i * 4) = s;
    }
}

// ---------- generic transpose: dst[n][k] (row len DK) = src[k][n]
__global__ __launch_bounds__(256) void transp_kernel(
    const float* __restrict__ src, short* __restrict__ dst, int RS, int CS, int DK)
{
    __shared__ float tb[64][65];
    const int kt = blockIdx.x * 64, nt = blockIdx.y * 64;
    const long sb = (long)blockIdx.z * RS * CS;
    const long db = (long)blockIdx.z * CS * DK;
    const int rr = threadIdx.x >> 6, cc = threadIdx.x & 63;
#pragma unroll
    for (int i = 0; i < 16; ++i) {
        int r = i * 4 + rr;
        int k = kt + r, n = nt + cc;
        tb[r][cc] = (k < RS && n < CS) ? src[sb + (long)k * CS + n] : 0.0f;
    }
    __syncthreads();
#pragma unroll
    for (int i = 0; i < 16; ++i) {
        int r = i * 4 + rr;
        int n = nt + r, k = kt + cc;
        if (n < CS && k < DK) dst[db + (long)n * DK + k] = f2bf(tb[cc][r]);
    }
}

// ---------- router weights: wrT[l][16][1024] = w_rimg[l][k][e] transposed, e>=8 zero
__global__ __launch_bounds__(256) void wrt_kernel(
    const float* __restrict__ w_rimg, short* __restrict__ wrT)
{
    const int l = blockIdx.x >> 4, e = blockIdx.x & 15;
    short* dst = wrT + ((long)l * 16 + e) * 1024;
    if (e < 8) {
        const float* src = w_rimg + (long)l * 8192 + e;
        for (int k = threadIdx.x; k < 1024; k += 256) dst[k] = f2bf(src[k * 8]);
    } else {
        for (int k = threadIdx.x; k < 1024; k += 256) dst[k] = 0;
    }
}

// ---------- in_proj MFMA GEMM
__global__ __launch_bounds__(256) void gemm_in_mfma(
    const short* __restrict__ Xb, const short* __restrict__ Wbt, short* __restrict__ Hb)
{
    __shared__ __align__(16) short As[128 * 32];
    __shared__ __align__(16) short Bs[128 * 32];
    const int tid = threadIdx.x;
    const int m0 = blockIdx.x * 128, n0 = blockIdx.y * 128;
    const int w = tid >> 6, lane = tid & 63;
    const int quad = lane >> 4, l15 = lane & 15;
    const int wm = (w >> 1) * 64, wn = (w & 1) * 64;

    floatx4 acc[4][4];
#pragma unroll
    for (int i = 0; i < 4; ++i)
#pragma unroll
        for (int j = 0; j < 4; ++j) acc[i][j] = 0.0f;

    const int r0 = tid >> 2, kof = (tid & 3) * 8;
    const int r1 = (tid + 256) >> 2;
    const short* a0p = Xb + (long)(m0 + r0) * KP + kof;
    const short* a1p = Xb + (long)(m0 + r1) * KP + kof;
    const short* b0p = Wbt + (long)(n0 + r0) * KP + kof;
    const short* b1p = Wbt + (long)(n0 + r1) * KP + kof;
    short* as0 = As + tid * 8;
    short* as1 = As + (tid + 256) * 8;
    short* bs0 = Bs + tid * 8;
    short* bs1 = Bs + (tid + 256) * 8;

    for (int k0 = 0; k0 < KP; k0 += 32) {
        __syncthreads();
        ASYNC16(a0p + k0, as0);
        ASYNC16(a1p + k0, as1);
        ASYNC16(b0p + k0, bs0);
        ASYNC16(b1p + k0, bs1);
        __syncthreads();
        bf16x8 af[4], bfr[4];
#pragma unroll
        for (int i = 0; i < 4; ++i)
            af[i] = *(const bf16x8*)&As[(wm + i * 16 + l15) * 32 + quad * 8];
#pragma unroll
        for (int j = 0; j < 4; ++j)
            bfr[j] = *(const bf16x8*)&Bs[(wn + j * 16 + l15) * 32 + quad * 8];
#pragma unroll
        for (int i = 0; i < 4; ++i)
#pragma unroll
            for (int j = 0; j < 4; ++j)
                acc[i][j] = __builtin_amdgcn_mfma_f32_16x16x32_bf16(af[i], bfr[j], acc[i][j], 0, 0, 0);
    }
#pragma unroll
    for (int i = 0; i < 4; ++i)
#pragma unroll
        for (int j = 0; j < 4; ++j)
#pragma unroll
            for (int r = 0; r < 4; ++r)
                Hb[(long)(m0 + wm + i * 16 + quad * 4 + r) * DM + n0 + wn + j * 16 + l15] =
                    f2bf(acc[i][j][r]);
}

// ---------- column mean
__global__ __launch_bounds__(256) void colmean_kernel(
    const short* __restrict__ Hb, float* __restrict__ outp)
{
    const int col = blockIdx.x * 256 + threadIdx.x;
    const int img = blockIdx.y;
    const int t0 = blockIdx.z * 256;
    const short* p = Hb + ((long)img * TPI + t0) * DM + col;
    float s = 0.0f;
#pragma unroll 8
    for (int t = 0; t < 256; ++t) s += bf2f(p[(long)t * DM]);
    atomicAdd(&outp[img * DM + col], s * (1.0f / 4096.0f));
}

// ---------- skin stage 1
__global__ __launch_bounds__(256) void skin1_kernel(
    const float* __restrict__ g, const float* __restrict__ w_sc1,
    const float* __restrict__ b_sc1, float* __restrict__ hsg)
{
    __shared__ float red[4][64];
    const int img = blockIdx.x;
    const int part = threadIdx.x >> 6, c = threadIdx.x & 63;
    float s = 0.0f;
    for (int i = 0; i < 256; ++i) {
        int d = part * 256 + i;
        s += g[img * DM + d] * w_sc1[d * 64 + c];
    }
    red[part][c] = s;
    __syncthreads();
    if (part == 0) {
        float v = red[0][c] + red[1][c] + red[2][c] + red[3][c] + b_sc1[c];
        hsg[img * 64 + c] = fmaxf(v, 0.0f);
    }
}

// ---------- skin stage 2
__global__ __launch_bounds__(256) void skin2_kernel(
    const float* __restrict__ hsg, const float* __restrict__ w_sc2, const float* __restrict__ b_sc2,
    const float* __restrict__ w_rskin, float* __restrict__ skin_logits_out, float* __restrict__ rb)
{
    __shared__ float l3[24];
    __shared__ float sp[24];
    const int tid = threadIdx.x;
    if (tid < 24) {
        int img = tid / 3, j = tid % 3;
        float s = b_sc2[j];
        for (int c = 0; c < 64; ++c) s += hsg[img * 64 + c] * w_sc2[c * 3 + j];
        l3[tid] = s;
        skin_logits_out[tid] = s;
    }
    __syncthreads();
    if (tid < 8) {
        float v0 = l3[tid * 3], v1 = l3[tid * 3 + 1], v2 = l3[tid * 3 + 2];
        float m = fmaxf(v0, fmaxf(v1, v2));
        float e0 = expf(v0 - m), e1 = expf(v1 - m), e2 = expf(v2 - m);
        float inv = 1.0f / (e0 + e1 + e2);
        sp[tid * 3] = e0 * inv; sp[tid * 3 + 1] = e1 * inv; sp[tid * 3 + 2] = e2 * inv;
    }
    __syncthreads();
    {
        int l = tid >> 6, img = (tid >> 3) & 7, e = tid & 7;
        float s = 0.0f;
#pragma unroll
        for (int c = 0; c < 3; ++c) s += sp[img * 3 + c] * w_rskin[(l * 3 + c) * 8 + e];
        rb[tid] = s;
    }
}

// ---------- MFMA router: logits = H[64,1024] @ wrT^T, softmax, top2, pair counts, aux
__global__ __launch_bounds__(256) void router_kernel(
    const short* __restrict__ Hb, const short* __restrict__ wrT, const float* __restrict__ rb,
    uint* __restrict__ top2e, float* __restrict__ top2w, int* __restrict__ counts_pair,
    float* __restrict__ sum_probs, float* __restrict__ mask_cnt, int l)
{
    __shared__ __align__(16) short As[8 * 64 * 32];   // [c][tok][32]
    __shared__ float lgS[64 * 9];
    const int tid = threadIdx.x;
    const int tok0 = blockIdx.x * 64;
    const int img = tok0 >> 12;
    const int w = tid >> 6, lane = tid & 63;
    const int quad = lane >> 4, l15 = lane & 15;

    const short* rowptr = Hb + (long)(tok0 + w * 16 + (lane >> 2)) * DM + (lane & 3) * 8;
    short* sdst = As + tid * 8;   // + c*2048
    const short* wrl = wrT + (long)l * 16 * 1024 + l15 * 1024 + quad * 8;

    floatx4 acc = 0.0f;
    for (int k0 = 0; k0 < DM; k0 += 256) {
        __syncthreads();
#pragma unroll
        for (int c = 0; c < 8; ++c) ASYNC16(rowptr + k0 + c * 32, sdst + c * 2048);
        __syncthreads();
#pragma unroll
        for (int c = 0; c < 8; ++c) {
            bf16x8 af = *(const bf16x8*)&As[c * 2048 + (w * 16 + l15) * 32 + quad * 8];
            bf16x8 bf = *(const bf16x8*)(wrl + k0 + c * 32);
            acc = __builtin_amdgcn_mfma_f32_16x16x32_bf16(af, bf, acc, 0, 0, 0);
        }
    }
    if (l15 < 8) {
#pragma unroll
        for (int r = 0; r < 4; ++r) lgS[(w * 16 + quad * 4 + r) * 9 + l15] = acc[r];
    }
    __syncthreads();

    if (tid < 64) {
        const int token = tok0 + tid;
        float p[8];
        float mx = -1e30f;
#pragma unroll
        for (int e = 0; e < 8; ++e) {
            float v = lgS[tid * 9 + e] + rb[l * 64 + img * 8 + e];
            p[e] = v; mx = fmaxf(mx, v);
        }
        float s = 0.0f;
#pragma unroll
        for (int e = 0; e < 8; ++e) { p[e] = expf(p[e] - mx); s += p[e]; }
        float inv = 1.0f / s;
#pragma unroll
        for (int e = 0; e < 8; ++e) p[e] *= inv;

        int i1 = 0; float b1v = p[0];
#pragma unroll
        for (int e = 1; e < 8; ++e) if (p[e] > b1v) { b1v = p[e]; i1 = e; }
        int i2 = -1; float b2v = -1.0f;
#pragma unroll
        for (int e = 0; e < 8; ++e) if (e != i1 && p[e] > b2v) { b2v = p[e]; i2 = e; }
        float den = b1v + b2v + 1e-6f;
        top2e[token] = (uint)i1 | ((uint)i2 << 8);
        top2w[2 * token] = b1v / den;
        top2w[2 * token + 1] = b2v / den;

        atomicAdd(&counts_pair[l * 64 + i1 * 8 + i2], 1);

        for (int slot = 0; slot < 2; ++slot) {
            int esel = slot ? i2 : i1;
#pragma unroll
            for (int e = 0; e < 8; ++e) {
                unsigned long long m = __ballot(esel == e);
                int pc = __popcll(m);
                if (pc && tid == (__ffsll(m) - 1))
                    atomicAdd(&mask_cnt[l * 64 + img * 8 + e], (float)pc);
            }
        }
#pragma unroll
        for (int e = 0; e < 8; ++e) {
            float r = p[e];
            for (int off = 32; off > 0; off >>= 1) r += __shfl_down(r, off);
            if (tid == 0) atomicAdd(&sum_probs[l * 64 + img * 8 + e], r);
        }
    }
}

// ---------- work queue + pair offsets (runs BEFORE scatter)
__global__ __launch_bounds__(64) void wq_kernel(
    const int* __restrict__ counts_pair, int* __restrict__ wq, int* __restrict__ nworkp,
    int* __restrict__ pair_off, int l)
{
    const int p = threadIdx.x;
    int cnt = counts_pair[l * 64 + p];
    // token-offset scan
    int x = cnt;
    for (int off = 1; off < 64; off <<= 1) {
        int y = __shfl_up(x, off);
        if (p >= off) x += y;
    }
    pair_off[p] = x - cnt;
    // tile scan
    int nb = (cnt + 63) >> 6;
    int t = nb;
    for (int off = 1; off < 64; off <<= 1) {
        int y = __shfl_up(t, off);
        if (p >= off) t += y;
    }
    int start = t - nb;
    for (int i = 0; i < nb; ++i) wq[start + i] = p | ((i * 64) << 6);
    if (p == 63) nworkp[0] = t;
}

// ---------- scatter by expert-pair
__global__ __launch_bounds__(256) void scatter_kernel(
    const uint* __restrict__ top2e, const float* __restrict__ top2w,
    const int* __restrict__ pair_off, int* __restrict__ cursors,
    int* __restrict__ btok, float* __restrict__ bw1, float* __restrict__ bw2, int l)
{
    const int t = blockIdx.x * 256 + threadIdx.x;
    const int lane = threadIdx.x & 63;
    uint pe = top2e[t];
    int p = (int)(pe & 255u) * 8 + (int)((pe >> 8) & 255u);
    float w1 = top2w[2 * t], w2 = top2w[2 * t + 1];
    int myoff = pair_off[p];
    unsigned long long rem = __ballot(true);
    while (rem) {
        int leader = __ffsll(rem) - 1;
        int pv = __shfl(p, leader);
        unsigned long long m = __ballot(p == pv);
        int basep = 0;
        if (lane == leader) basep = atomicAdd(&cursors[l * 64 + pv], __popcll(m));
        basep = __shfl(basep, leader);
        if (p == pv) {
            int pos = basep + __popcll(m & ((1ull << lane) - 1ull));
            int s = myoff + pos;
            btok[s] = t;
            bw1[s] = w1;
            bw2[s] = w2;
        }
        rem &= ~m;
    }
}

// ---------- fused pair-expert MLP, 256-wide k-slabs, LDS-accumulated output
__global__ __launch_bounds__(256) void expert_pair(
    const short* __restrict__ Hin, short* __restrict__ Hout,
    const int* __restrict__ counts_pair, const int* __restrict__ pair_off,
    const int* __restrict__ btok, const float* __restrict__ bw1, const float* __restrict__ bw2,
    const short* __restrict__ ew1t, const float* __restrict__ eb1,
    const short* __restrict__ ew2t, const float* __restrict__ eb2,
    const int* __restrict__ wq, const int* __restrict__ nworkp, int l)
{
    __shared__ __align__(16) short As[8 * 64 * 32];   // [c][tok][32] : k-slab / residual / output
    __shared__ __align__(16) short h1a[64 * 72];
    __shared__ __align__(16) short h1b[64 * 72];
    __shared__ int tkS[64];
    __shared__ float w1S[64], w2S[64];

    const int tid = threadIdx.x;
    const int w = tid >> 6, lane = tid & 63;
    const int quad = lane >> 4, l15 = lane & 15;
    const int nwork = nworkp[0];
    short* sdst = As + tid * 8;   // + c*2048

    for (int wi = blockIdx.x; wi < nwork; wi += gridDim.x) {
        const int item = wq[wi];
        const int p = item & 63, base = item >> 6;
        const int ea = p >> 3, eb = p & 7;
        const int off = pair_off[p];
        const int cnt = counts_pair[l * 64 + p];

        __syncthreads();
        if (tid < 64) {
            bool valid = (base + tid) < cnt;
            int s = off + base + tid;
            tkS[tid] = valid ? btok[s] : 0;
            w1S[tid] = valid ? bw1[s] : 0.0f;
            w2S[tid] = valid ? bw2[s] : 0.0f;
        }
        __syncthreads();
        const int lea = l * 8 + ea, leb = l * 8 + eb;
        const short* rowptr = Hin + (long)tkS[w * 16 + (lane >> 2)] * DM + (lane & 3) * 8;

        // ---- phase 1: h1 = relu(H @ W1 + b1) for both experts
        floatx4 acc1a[4], acc1b[4];
#pragma unroll
        for (int i = 0; i < 4; ++i) { acc1a[i] = 0.0f; acc1b[i] = 0.0f; }
        const short* w1ap = ew1t + ((long)lea * 64 + w * 16 + l15) * DM + quad * 8;
        const short* w1bp = ew1t + ((long)leb * 64 + w * 16 + l15) * DM + quad * 8;

        for (int k0 = 0; k0 < DM; k0 += 256) {
            __syncthreads();
#pragma unroll
            for (int c = 0; c < 8; ++c) ASYNC16(rowptr + k0 + c * 32, sdst + c * 2048);
            __syncthreads();
#pragma unroll
            for (int c = 0; c < 8; ++c) {
                bf16x8 ba = *(const bf16x8*)(w1ap + k0 + c * 32);
                bf16x8 bb = *(const bf16x8*)(w1bp + k0 + c * 32);
#pragma unroll
                for (int i = 0; i < 4; ++i) {
                    bf16x8 af = *(const bf16x8*)&As[c * 2048 + (i * 16 + l15) * 32 + quad * 8];
                    acc1a[i] = __builtin_amdgcn_mfma_f32_16x16x32_bf16(af, ba, acc1a[i], 0, 0, 0);
                    acc1b[i] = __builtin_amdgcn_mfma_f32_16x16x32_bf16(af, bb, acc1b[i], 0, 0, 0);
                }
            }
        }
        {
            float b1av = eb1[lea * BN + w * 16 + l15];
            float b1bv = eb1[leb * BN + w * 16 + l15];
#pragma unroll
            for (int i = 0; i < 4; ++i)
#pragma unroll
                for (int r = 0; r < 4; ++r) {
                    h1a[(i * 16 + quad * 4 + r) * 72 + w * 16 + l15] =
                        f2bf(fmaxf(acc1a[i][r] + b1av, 0.0f));
                    h1b[(i * 16 + quad * 4 + r) * 72 + w * 16 + l15] =
                        f2bf(fmaxf(acc1b[i][r] + b1bv, 0.0f));
                }
        }
        __syncthreads();   // h1 visible; As free

        // ---- phase 2: 4 n-groups of 256 cols
        const short* w2ap = ew2t + ((long)lea * DM + w * 16 + l15) * 64 + quad * 8;
        const short* w2bp = ew2t + ((long)leb * DM + w * 16 + l15) * 64 + quad * 8;
        const bool rowvalid = (base + (tid >> 2)) < cnt;
        const long orow = (long)tkS[tid >> 2] * DM;

        for (int gidx = 0; gidx < 4; ++gidx) {
            const int g0 = gidx * 256;
            // stage residual slab
#pragma unroll
            for (int c = 0; c < 8; ++c) ASYNC16(rowptr + g0 + c * 32, sdst + c * 2048);
            __syncthreads();
            // 4 n-slices of 64
#pragma unroll
            for (int ns = 0; ns < 4; ++ns) {
                const int n0 = g0 + ns * 64;
                floatx4 a2a[4], a2b[4];
#pragma unroll
                for (int tj = 0; tj < 4; ++tj) { a2a[tj] = 0.0f; a2b[tj] = 0.0f; }
#pragma unroll
                for (int kk = 0; kk < 2; ++kk) {
                    bf16x8 wa = *(const bf16x8*)(w2ap + (long)n0 * 64 + kk * 32);
                    bf16x8 wb = *(const bf16x8*)(w2bp + (long)n0 * 64 + kk * 32);
#pragma unroll
                    for (int tj = 0; tj < 4; ++tj) {
                        bf16x8 ha = *(const bf16x8*)&h1a[(tj * 16 + l15) * 72 + kk * 32 + quad * 8];
                        bf16x8 hb = *(const bf16x8*)&h1b[(tj * 16 + l15) * 72 + kk * 32 + quad * 8];
                        a2a[tj] = __builtin_amdgcn_mfma_f32_16x16x32_bf16(wa, ha, a2a[tj], 0, 0, 0);
                        a2b[tj] = __builtin_amdgcn_mfma_f32_16x16x32_bf16(wb, hb, a2b[tj], 0, 0, 0);
                    }
                }
                const int nloc = ns * 64 + w * 16 + quad * 4;   // col within group
                const int csub = nloc >> 5, cidx = nloc & 31;
                float4 b2av = *(const float4*)&eb2[lea * DM + g0 + nloc];
                float4 b2bv = *(const float4*)&eb2[leb * DM + g0 + nloc];
#pragma unroll
                for (int tj = 0; tj < 4; ++tj) {
                    int tk = tj * 16 + l15;
                    float w1 = w1S[tk], w2 = w2S[tk];
                    short* slot = &As[csub * 2048 + tk * 32 + cidx];
                    short4 res = *(short4*)slot;
                    short4 o;
                    o.x = f2bf(bf2f(res.x) + w1 * (a2a[tj][0] + b2av.x) + w2 * (a2b[tj][0] + b2bv.x));
                    o.y = f2bf(bf2f(res.y) + w1 * (a2a[tj][1] + b2av.y) + w2 * (a2b[tj][1] + b2bv.y));
                    o.z = f2bf(bf2f(res.z) + w1 * (a2a[tj][2] + b2av.z) + w2 * (a2b[tj][2] + b2bv.z));
                    o.w = f2bf(bf2f(res.w) + w1 * (a2a[tj][3] + b2av.w) + w2 * (a2b[tj][3] + b2bv.w));
                    *(short4*)slot = o;
                }
            }
            __syncthreads();   // output slab complete
            // write group: thread -> row tid>>2, col quarter tid&3 (2 sub-slabs x 64B)
            if (rowvalid) {
                const int tok = tid >> 2;
#pragma unroll
                for (int c2 = 0; c2 < 2; ++c2) {
                    const int csub = (tid & 3) * 2 + c2;
#pragma unroll
                    for (int j = 0; j < 4; ++j) {
                        int4 v = *(const int4*)&As[csub * 2048 + tok * 32 + j * 8];
                        *(int4*)(Hout + orow + g0 + csub * 32 + j * 8) = v;
                    }
                }
            }
            __syncthreads();   // As free for next group
        }
    }
}

// ---------- vision_proj
__global__ __launch_bounds__(256) void vproj_kernel(
    const float* __restrict__ pooled, const float* __restrict__ w_out,
    const float* __restrict__ b_out, float* __restrict__ outp)
{
    __shared__ float ps[8 * 128];
    const int tid = threadIdx.x;
    const int n = blockIdx.x * 256 + tid;
    const int d0 = blockIdx.y * 128;
#pragma unroll
    for (int i = 0; i < 4; ++i) {
        int idx = tid + i * 256;
        ps[idx] = pooled[(idx >> 7) * DM + d0 + (idx & 127)];
    }
    __syncthreads();
    float acc[8];
    float binit = (blockIdx.y == 0) ? b_out[n] : 0.0f;
#pragma unroll
    for (int img = 0; img < 8; ++img) acc[img] = binit;
    for (int d = 0; d < 128; ++d) {
        float wv = w_out[(long)(d0 + d) * DOUT + n];
#pragma unroll
        for (int img = 0; img < 8; ++img) acc[img] += ps[img * 128 + d] * wv;
    }
#pragma unroll
    for (int img = 0; img < 8; ++img) atomicAdd(&outp[img * DOUT + n], acc[img]);
}

// ---------- aux
__global__ __launch_bounds__(64) void aux_kernel(
    const float* __restrict__ sum_probs, const float* __restrict__ mask_cnt,
    float* __restrict__ outp)
{
    const int tid = threadIdx.x;
    float v = 0.0f;
    if (tid < 32) {
        float s = 0.0f;
#pragma unroll
        for (int e = 0; e < 8; ++e) s += sum_probs[tid * 8 + e] * mask_cnt[tid * 8 + e];
        v = s * (8.0f / (4096.0f * 4096.0f));
    }
    for (int off = 32; off > 0; off >>= 1) v += __shfl_down(v, off);
    if (tid == 0) outp[0] = v;
}

extern "C" void kernel_launch(void* const* d_in, const int* in_sizes, int n_in,
                              void* d_out, int out_size, void* d_ws, size_t ws_size,
                              hipStream_t stream) {
    const float* X       = (const float*)d_in[0];
    const float* w_in    = (const float*)d_in[2];
    const float* w_sc1   = (const float*)d_in[3];
    const float* b_sc1   = (const float*)d_in[4];
    const float* w_sc2   = (const float*)d_in[5];
    const float* b_sc2   = (const float*)d_in[6];
    const float* w_rimg  = (const float*)d_in[7];
    const float* w_rskin = (const float*)d_in[8];
    const float* ew1     = (const float*)d_in[9];
    const float* eb1     = (const float*)d_in[10];
    const float* ew2     = (const float*)d_in[11];
    const float* eb2     = (const float*)d_in[12];
    const float* w_out   = (const float*)d_in[13];
    const float* b_out   = (const float*)d_in[14];

    float* out = (float*)d_out;
    char* ws = (char*)d_ws;

    short* H0   = (short*)(ws + OFF_H0);
    short* H1   = (short*)(ws + OFF_H1);
    short* Xb   = (short*)(ws + OFF_XB);
    short* Wbt  = (short*)(ws + OFF_WBT);
    short* ew1t = (short*)(ws + OFF_E1T);
    short* ew2t = (short*)(ws + OFF_E2T);
    int*   btok = (int*)(ws + OFF_BTOK);
    float* bw1  = (float*)(ws + OFF_BW1);
    float* bw2  = (float*)(ws + OFF_BW2);
    uint*  top2e = (uint*)(ws + OFF_T2E);
    float* top2w = (float*)(ws + OFF_T2W);
    int*   wq    = (int*)(ws + OFF_WQ);
    int*   counts_pair = (int*)(ws + OFF_Z);
    int*   cursors     = (int*)(ws + OFF_Z + 1024);
    int*   nworkp      = (int*)(ws + OFF_Z + 2048);
    int*   pair_off    = (int*)(ws + OFF_Z + 2112);
    float* sum_probs   = (float*)(ws + OFF_Z + 2368);
    float* mask_cnt    = (float*)(ws + OFF_Z + 3392);
    float* g           = (float*)(ws + OFF_Z + 4416);
    float* hsg         = (float*)(ws + OFF_Z + 37184);
    float* rb          = (float*)(ws + OFF_RB);
    short* wrT         = (short*)(ws + OFF_WRT);

    hipMemsetAsync(d_out, 0, (size_t)out_size * sizeof(float), stream);
    hipMemsetAsync(ws + OFF_Z, 0, Z_BYTES, stream);

    dim3 b256(256);
    convx_kernel<<<TT, b256, 0, stream>>>(X, Xb);
    transp_kernel<<<dim3(19, 16, 1), b256, 0, stream>>>(w_in, Wbt, DIN, DM, KP);
    transp_kernel<<<dim3(16, 1, 32), b256, 0, stream>>>(ew1, ew1t, DM, BN, DM);
    transp_kernel<<<dim3(1, 16, 32), b256, 0, stream>>>(ew2, ew2t, BN, DM, BN);
    wrt_kernel<<<64, b256, 0, stream>>>(w_rimg, wrT);
    gemm_in_mfma<<<dim3(256, 8), b256, 0, stream>>>(Xb, Wbt, H0);
    colmean_kernel<<<dim3(4, 8, 16), b256, 0, stream>>>(H0, g);
    skin1_kernel<<<8, b256, 0, stream>>>(g, w_sc1, b_sc1, hsg);
    skin2_kernel<<<1, b256, 0, stream>>>(hsg, w_sc2, b_sc2, w_rskin, out + 40961, rb);

    short* Hc = H0;
    short* Hn = H1;
    for (int l = 0; l < NL; ++l) {
        router_kernel<<<512, b256, 0, stream>>>(Hc, wrT, rb, top2e, top2w,
                                                counts_pair, sum_probs, mask_cnt, l);
        wq_kernel<<<1, 64, 0, stream>>>(counts_pair, wq, nworkp, pair_off, l);
        scatter_kernel<<<128, b256, 0, stream>>>(top2e, top2w, pair_off, cursors,
                                                 btok, bw1, bw2, l);
        expert_pair<<<576, b256, 0, stream>>>(Hc, Hn, counts_pair, pair_off, btok, bw1, bw2,
                                              ew1t, eb1, ew2t, eb2, wq, nworkp, l);
        short* tmp = Hc; Hc = Hn; Hn = tmp;
    }
    colmean_kernel<<<dim3(4, 8, 16), b256, 0, stream>>>(Hc, out);
    vproj_kernel<<<dim3(16, 8), b256, 0, stream>>>(out, w_out, b_out, out + 8192);
    aux_kernel<<<1, 64, 0, stream>>>(sum_probs, mask_cnt, out + 40960);
}